// Round 6
// baseline (545.346 us; speedup 1.0000x reference)
//
#include <hip/hip_runtime.h>

// Power retention (deg-2), B=2 T=4096 H=16 D=64, CHUNK=64, E=2080.
// Round 9: R8 base + three surgical scan changes:
//  (a) __launch_bounds__(512,2): R8's (512,4) forced VGPR<=64 and spilled
//      (~55MB excess WRITE_SIZE). 128 VGPR still gives 4 waves/SIMD =
//      2 blocks/CU, which is all the 512-block grid can use anyway.
//  (b) MM1 is now done by waves 0-3 only, each computing BOTH n-tiles from
//      one A-fragment (halves qiu/qrow LDS reads; waves 4-7 wait at B2).
//      Barriers remain in workgroup-uniform control flow.
//  (c) MM2 skipped at n=63 (its sT/sk writes were never read).
// prep + intra_merge unchanged from R8.

#define B_ 2
#define T_ 4096
#define H_ 16
#define D_ 64
#define CHUNK_ 64
#define NCH_ 64
#define E_ 2080
#define EH_ 8
#define NBLK_ 36         // (i, jb) 8-wide blocks per eh-slice (288/8, exact)
#define EPAD_ 288        // NBLK_*8
#define NKS_ 9           // MM1 K-steps of 32
#define STR_ 296         // sT row stride (f16), 592B
#define OUTN_ 8388608    // B*T*H*D

typedef __attribute__((ext_vector_type(8))) _Float16 half8v;
typedef __attribute__((ext_vector_type(4))) float floatx4;

union U8 { half8v h; unsigned u[4]; ushort s[8]; };

static __device__ __forceinline__ float wave_iscan(float g, int lane) {
    #pragma unroll
    for (int off = 1; off < 64; off <<= 1) {
        float o = __shfl_up(g, off, 64);
        if (lane >= off) g += o;
    }
    return g;
}

typedef const __attribute__((address_space(1))) unsigned int* gas1_t;
typedef __attribute__((address_space(3))) unsigned int* las3_t;
static __device__ __forceinline__ void gload16(const void* g, void* l) {
    __builtin_amdgcn_global_load_lds((gas1_t)g, (las3_t)l, 16, 0, 0);
}

// ---------------- Prep: gates + scales + cvt + swizzled transpose ----------------
// qh : [bh][n][c][ ((d>>3) ^ (c&7))*8 + (d&7) ]            q~ = 0.125*exp(0.5*cg)*q
// kh : [bh][n][c][ ((d>>3) ^ (c&7))*8 + (d&7) ]            k~ = exp(0.5*(gs-cg))*k
// khT: [bh][n][d][ ((c>>3) ^ (d&7) ^ (d>>3))*8 + (c&7) ]
// vhT: [bh][n][d][ ((c>>3) ^ (dl&7) ^ (dl>>3))*8 + (c&7) ] dl = d&31 (dh halves)
__global__ __launch_bounds__(256) void prep_kernel(
    const float* __restrict__ q, const float* __restrict__ k, const float* __restrict__ v,
    const float* __restrict__ gate,
    _Float16* __restrict__ qh, _Float16* __restrict__ kh, _Float16* __restrict__ khT,
    _Float16* __restrict__ vhT, float* __restrict__ gse_buf)
{
    const int bid = blockIdx.x;          // bh*64 + n
    const int bh = bid >> 6, n = bid & 63;
    const int b = bh >> 4, h = bh & 15;
    const int t0 = n * CHUNK_;
    const int tid = threadIdx.x;

    __shared__ float cgs[64];
    __shared__ float tbuf[64 * 68];

    if (tid < 64) {
        float g = gate[((size_t)(b * T_ + t0) + tid) * H_ + h];
        cgs[tid] = wave_iscan(g, tid);
    }
    __syncthreads();
    const float gs = cgs[63];
    if (tid == 0) gse_buf[bid] = __expf(gs);

    const int c = tid >> 2, dq = (tid & 3) * 16;
    const size_t gbase = ((size_t)(b * T_ + t0 + c) * H_ + h) * 64 + dq;
    const size_t obase = (size_t)bid * 4096;

    // ---- q~ (no transpose, swizzled d-groups)
    {
        float qsc = 0.125f * __expf(0.5f * cgs[c]);
        #pragma unroll
        for (int g8 = 0; g8 < 2; ++g8) {
            float4 a0 = *(const float4*)(q + gbase + g8 * 8);
            float4 a1 = *(const float4*)(q + gbase + g8 * 8 + 4);
            half8v hv;
            hv[0] = (_Float16)(a0.x * qsc); hv[1] = (_Float16)(a0.y * qsc);
            hv[2] = (_Float16)(a0.z * qsc); hv[3] = (_Float16)(a0.w * qsc);
            hv[4] = (_Float16)(a1.x * qsc); hv[5] = (_Float16)(a1.y * qsc);
            hv[6] = (_Float16)(a1.z * qsc); hv[7] = (_Float16)(a1.w * qsc);
            int grp = (dq >> 3) + g8;
            *(half8v*)&qh[obase + (size_t)(c * 64) + ((grp ^ (c & 7)) << 3)] = hv;
        }
    }
    // ---- k~ -> kh (row-major, q-style swizzle) + LDS [c][d]
    {
        float ksc = __expf(0.5f * (gs - cgs[c]));
        float4 sa[4];
        #pragma unroll
        for (int i = 0; i < 4; ++i) {
            float4 a = *(const float4*)(k + gbase + i * 4);
            sa[i].x = a.x * ksc; sa[i].y = a.y * ksc;
            sa[i].z = a.z * ksc; sa[i].w = a.w * ksc;
            *(float4*)&tbuf[c * 68 + dq + i * 4] = sa[i];
        }
        #pragma unroll
        for (int g8 = 0; g8 < 2; ++g8) {
            half8v hv;
            hv[0] = (_Float16)sa[g8 * 2].x;     hv[1] = (_Float16)sa[g8 * 2].y;
            hv[2] = (_Float16)sa[g8 * 2].z;     hv[3] = (_Float16)sa[g8 * 2].w;
            hv[4] = (_Float16)sa[g8 * 2 + 1].x; hv[5] = (_Float16)sa[g8 * 2 + 1].y;
            hv[6] = (_Float16)sa[g8 * 2 + 1].z; hv[7] = (_Float16)sa[g8 * 2 + 1].w;
            int grp = (dq >> 3) + g8;
            *(half8v*)&kh[obase + (size_t)(c * 64) + ((grp ^ (c & 7)) << 3)] = hv;
        }
    }
    __syncthreads();
    {   // transposed, swizzled store of k~^T
        int d = tid & 63, f = (d & 7) ^ (d >> 3);
        #pragma unroll
        for (int gg = 0; gg < 2; ++gg) {
            int cg = (tid >> 6) * 2 + gg;
            half8v hv;
            #pragma unroll
            for (int j = 0; j < 8; ++j) hv[j] = (_Float16)tbuf[(cg * 8 + j) * 68 + d];
            *(half8v*)&khT[obase + (size_t)(d * 64) + ((cg ^ f) << 3)] = hv;
        }
    }
    __syncthreads();
    {   // v -> LDS (no scale)
        #pragma unroll
        for (int i = 0; i < 4; ++i)
            *(float4*)&tbuf[c * 68 + dq + i * 4] = *(const float4*)(v + gbase + i * 4);
    }
    __syncthreads();
    {   // transposed, swizzled store of v^T (f over dl = d&31)
        int d = tid & 63, dl = d & 31, f = (dl & 7) ^ (dl >> 3);
        #pragma unroll
        for (int gg = 0; gg < 2; ++gg) {
            int cg = (tid >> 6) * 2 + gg;
            half8v hv;
            #pragma unroll
            for (int j = 0; j < 8; ++j) hv[j] = (_Float16)tbuf[(cg * 8 + j) * 68 + d];
            *(half8v*)&vhT[obase + (size_t)(d * 64) + ((cg ^ f) << 3)] = hv;
        }
    }
}

// ---------------- Kernel B: sequential scan over chunks (f16 MFMA) ----------------
__global__ __launch_bounds__(512, 2) void scan_kernel(
    const _Float16* __restrict__ qh, const _Float16* __restrict__ khT,
    const _Float16* __restrict__ vhT, const float* __restrict__ gse_buf,
    const float* __restrict__ S0, const float* __restrict__ sk0,
    float* __restrict__ den_buf, _Float16* __restrict__ part)
{
    const int bid = blockIdx.x;
    // XCD swizzle: all 16 blocks of one bh share bid%8 -> same XCD for q/k/v L2 reuse
    const int bh = (bid & 7) * 4 + (bid >> 7);
    const int inner = (bid >> 3) & 15;
    const int eh = inner & 7, dh = inner >> 3;
    const int tid = threadIdx.x, lane = tid & 63, w = tid >> 6;   // w 0..7
    const int nlane = lane & 15, quad = lane >> 4;

    __shared__ __align__(16) _Float16 sT[32 * STR_];     // S^T[d_local][e], 2-bit XOR swz
    __shared__ __align__(16) _Float16 kTs[64 * 64];      // k~^T (linear, global-preswizzled)
    __shared__ __align__(16) _Float16 qsh[64 * 64];      // q~   (linear, global-preswizzled)
    __shared__ __align__(16) _Float16 vTs[32 * 64];      // v^T half (linear, preswizzled)
    __shared__ __align__(16) _Float16 sk_s[EPAD_];
    __shared__ int blk_s[NBLK_];                         // i | (jb<<8)

    // ---- build (i, jb) block table for this slice
    for (int t = tid; t < NBLK_; t += 512) {
        int g = eh * NBLK_ + t;
        int i = 0;
        while (g >= 8 - (i >> 3)) { g -= 8 - (i >> 3); ++i; }
        int jb = (i >> 3) + g;
        blk_s[t] = i | (jb << 8);
    }
    __syncthreads();

    const _Float16* qsrc = qh + (size_t)(bh * NCH_) * 4096;
    const _Float16* ksrc = khT + (size_t)(bh * NCH_) * 4096;
    const _Float16* vsrc = vhT + (size_t)(bh * NCH_) * 4096 + dh * 2048;

    // issue q~(0) staging now; drains at the pre-loop barrier
    gload16(qsrc + tid * 8, &qsh[tid * 8]);

    // ---- sk init (sqrt2 fold; invalid slots stay 0 forever -> no m8 mask needed)
    for (int e = tid; e < EPAD_; e += 512) {
        int bv = blk_s[e >> 3];
        int i = bv & 255, j8 = (bv >> 8) * 8 + (e & 7);
        float sv = 0.f;
        if (j8 >= i) {
            int er = (i * (129 - i)) / 2 + (j8 - i);
            float coef = (j8 == i) ? 1.f : 1.41421356237f;
            sv = sk0[(size_t)bh * E_ + er] * coef;
        }
        sk_s[e] = (_Float16)sv;
    }
    // ---- sT init (f16 copy of S-hat = coef * S0), 2-bit XOR swizzled columns
    for (int p = tid; p < 32 * EPAD_; p += 512) {
        int dl = p / EPAD_;
        int e = p - dl * EPAD_;
        int bv = blk_s[e >> 3];
        int i = bv & 255, j8 = (bv >> 8) * 8 + (e & 7);
        float sv = 0.f;
        if (j8 >= i) {
            int er = (i * (129 - i)) / 2 + (j8 - i);
            float coef = (j8 == i) ? 1.f : 1.41421356237f;
            sv = S0[((size_t)bh * E_ + er) * 64 + dh * 32 + dl] * coef;
        }
        int col8 = e >> 3, gsw = (dl >> 2) & 3;
        int pc = ((col8 & ~3) | ((col8 & 3) ^ gsw)) * 8 + (e & 7);
        sT[dl * STR_ + pc] = (_Float16)sv;
    }

    // ---- wave roles: waves 0-3 = MM1 (m-tile w, both n-tiles); all 8 = MM2
    const int mt = w & 3;
    const int c_row = mt * 16 + nlane;
    const bool mm1_w = (w < 4);
    const bool den_w = mm1_w && (dh == 0);
    const int NTS = (w < 2) ? 3 : 2;          // MM2: waves 0,1 own a 3rd tile (16,17)

    // ---- resident S fragments: wave owns tiles {w, w+8, (w+16 if w<2)} x mtv{0,1}(+sk)
    floatx4 res[3][2];
    floatx4 resk[3];
    #pragma unroll
    for (int ts = 0; ts < 3; ++ts) {
        res[ts][0] = (floatx4){0.f, 0.f, 0.f, 0.f};
        res[ts][1] = (floatx4){0.f, 0.f, 0.f, 0.f};
        resk[ts]   = (floatx4){0.f, 0.f, 0.f, 0.f};
        if (ts >= NTS) continue;
        int tile = w + 8 * ts;
        int e = tile * 16 + nlane;
        int bv = blk_s[e >> 3];
        int i = bv & 255, j8 = (bv >> 8) * 8 + (e & 7);
        if (j8 >= i) {
            int er = (i * (129 - i)) / 2 + (j8 - i);
            float coef = (j8 == i) ? 1.f : 1.41421356237f;
            #pragma unroll
            for (int m = 0; m < 2; ++m) {
                floatx4 t4 = *(const floatx4*)&S0[((size_t)bh * E_ + er) * 64 + dh * 32 + m * 16 + quad * 4];
                #pragma unroll
                for (int r = 0; r < 4; ++r) res[ts][m][r] = t4[r] * coef;
            }
            if (dh == 0 && quad == 0) resk[ts][0] = sk0[(size_t)bh * E_ + er] * coef;
        }
    }

    // ---- chunk-invariant MM1 addresses (byte offsets)
    int qiu_off[NKS_], qrow_off[NKS_];
    #pragma unroll
    for (int ks = 0; ks < NKS_; ++ks) {
        int bv = blk_s[ks * 4 + quad];
        int ib = bv & 255, jb = bv >> 8;
        qiu_off[ks]  = (c_row * 64 + (((ib >> 3) ^ (c_row & 7)) << 3) + (ib & 7)) * 2;
        qrow_off[ks] = (c_row * 64 + ((jb ^ (c_row & 7)) << 3)) * 2;
    }
    const int swzb = (quad ^ ((nlane >> 2) & 3)) << 3;
    const int b0o0 = (nlane * STR_ + swzb) * 2;
    const int b0o1 = ((16 + nlane) * STR_ + swzb) * 2;

    // ---- chunk-invariant MM2 addresses + m2 splats
    int pa_off[3], pb_off[3], stw_off[3], eidx[3];
    unsigned m2sp[3];
    #pragma unroll
    for (int ts = 0; ts < 3; ++ts) {
        pa_off[ts] = pb_off[ts] = stw_off[ts] = eidx[ts] = 0; m2sp[ts] = 0;
        if (ts >= NTS) continue;
        int tile = w + 8 * ts, e = tile * 16 + nlane;
        int bv = blk_s[e >> 3];
        int ib = bv & 255, j8 = (bv >> 8) * 8 + (e & 7);
        int fib = (ib & 7) ^ (ib >> 3), fj8 = (j8 & 7) ^ (j8 >> 3);
        pa_off[ts] = (ib * 64 + ((quad ^ fib) << 3)) * 2;
        pb_off[ts] = (j8 * 64 + ((quad ^ fj8) << 3)) * 2;
        int col8 = e >> 3;
        int pc = ((col8 & ~3) | ((col8 & 3) ^ quad)) * 8 + (e & 7);
        stw_off[ts] = (quad * 4 * STR_ + pc) * 2;
        eidx[ts] = e;
        unsigned hv = (j8 < ib) ? 0u : ((j8 == ib) ? 0x3C00u : 0x4000u);  // {0,1,2} coef^2
        m2sp[ts] = (hv << 16) | hv;
    }
    int af_off[2];
    #pragma unroll
    for (int m = 0; m < 2; ++m) {
        int row = m * 16 + nlane;
        int fr = (row & 7) ^ (row >> 3);
        af_off[m] = (row * 64 + ((quad ^ fr) << 3)) * 2;
    }
    half8v af_sk = (half8v){0, 0, 0, 0, 0, 0, 0, 0};
    if (nlane == 0) af_sk = (half8v){1, 1, 1, 1, 1, 1, 1, 1};

    _Float16* ppart = part + (size_t)eh * OUTN_ + (((size_t)bh * T_) << 6) + dh * 32 + nlane;

    __syncthreads();   // B0: init + blk reads done; q~(0) drained

    for (int n = 0; n < NCH_; ++n) {
        // issue k~/v staging for THIS chunk; drains at B2 (hidden under MM1)
        gload16(ksrc + (size_t)n * 4096 + tid * 8, &kTs[tid * 8]);
        if (tid < 256) gload16(vsrc + (size_t)n * 4096 + tid * 8, &vTs[tid * 8]);
        const float gsev = gse_buf[bh * NCH_ + n];

        // ======== MM1 (waves 0-3): num[c][d] = pq . S-hat, both n-tiles;
        //          den rides as MFMA with sk column
        if (mm1_w) {
            floatx4 acc0 = {0.f, 0.f, 0.f, 0.f};
            floatx4 acc1 = {0.f, 0.f, 0.f, 0.f};
            floatx4 accd = {0.f, 0.f, 0.f, 0.f};
            #pragma unroll
            for (int ks = 0; ks < NKS_; ++ks) {
                ushort qiu = *(const ushort*)((const char*)qsh + qiu_off[ks]);
                unsigned qi2 = ((unsigned)qiu << 16) | qiu;
                U8 qv; qv.u[0] = qi2; qv.u[1] = qi2; qv.u[2] = qi2; qv.u[3] = qi2;
                half8v qrow = *(const half8v*)((const char*)qsh + qrow_off[ks]);
                half8v afr = qv.h * qrow;            // pq fragment, built once
                half8v b00 = *(const half8v*)((const char*)sT + b0o0 + ks * 64);
                half8v b01 = *(const half8v*)((const char*)sT + b0o1 + ks * 64);
                acc0 = __builtin_amdgcn_mfma_f32_16x16x32_f16(afr, b00, acc0, 0, 0, 0);
                acc1 = __builtin_amdgcn_mfma_f32_16x16x32_f16(afr, b01, acc1, 0, 0, 0);
                if (den_w) {
                    half8v b1 = (half8v){0, 0, 0, 0, 0, 0, 0, 0};
                    if (nlane == 0) b1 = *(const half8v*)&sk_s[ks * 32 + quad * 8];
                    accd = __builtin_amdgcn_mfma_f32_16x16x32_f16(afr, b1, accd, 0, 0, 0);
                }
            }
            _Float16* pp = ppart + ((size_t)(n * CHUNK_ + mt * 16 + quad * 4) << 6);
            #pragma unroll
            for (int r = 0; r < 4; ++r) {
                pp[(size_t)r << 6] = (_Float16)acc0[r];
                pp[((size_t)r << 6) + 16] = (_Float16)acc1[r];
            }
            if (den_w && nlane == 0) {
                #pragma unroll
                for (int r = 0; r < 4; ++r)
                    atomicAdd(&den_buf[(size_t)bh * T_ + n * CHUNK_ + mt * 16 + quad * 4 + r], accd[r]);
            }
        }
        __syncthreads();   // B2: MM1 LDS reads done; k~/v staged

        // issue q~(n+1); drains at B1 (hidden under MM2)
        if (n + 1 < NCH_) gload16(qsrc + (size_t)(n + 1) * 4096 + tid * 8, &qsh[tid * 8]);

        // ======== MM2 (all 8 waves): S-hat = gse*S-hat + v^T . pk
        //          (skipped at n=63: that state is never read)
        if (n < NCH_ - 1) {
            #pragma unroll
            for (int ts = 0; ts < 3; ++ts) {
                if (ts >= NTS) continue;
                #pragma unroll
                for (int m = 0; m < 2; ++m)
                    #pragma unroll
                    for (int r = 0; r < 4; ++r) res[ts][m][r] *= gsev;
                if (dh == 0) resk[ts][0] *= gsev;
            }
            #pragma unroll
            for (int k2 = 0; k2 < 2; ++k2) {
                const int xo = k2 * 64;    // group bit2 flip == byte bit6 flip
                half8v af0 = *(const half8v*)((const char*)vTs + (af_off[0] ^ xo));
                half8v af1 = *(const half8v*)((const char*)vTs + (af_off[1] ^ xo));
                #pragma unroll
                for (int ts = 0; ts < 3; ++ts) {
                    if (ts >= NTS) continue;
                    half8v pa = *(const half8v*)((const char*)kTs + (pa_off[ts] ^ xo));
                    half8v pb = *(const half8v*)((const char*)kTs + (pb_off[ts] ^ xo));
                    U8 mv; mv.u[0] = m2sp[ts]; mv.u[1] = m2sp[ts]; mv.u[2] = m2sp[ts]; mv.u[3] = m2sp[ts];
                    half8v bfr = pa * pb * mv.h;
                    res[ts][0] = __builtin_amdgcn_mfma_f32_16x16x32_f16(af0, bfr, res[ts][0], 0, 0, 0);
                    res[ts][1] = __builtin_amdgcn_mfma_f32_16x16x32_f16(af1, bfr, res[ts][1], 0, 0, 0);
                    if (dh == 0)
                        resk[ts] = __builtin_amdgcn_mfma_f32_16x16x32_f16(af_sk, bfr, resk[ts], 0, 0, 0);
                }
            }
            // write back sT (swizzled, 2-way max) and sk
            #pragma unroll
            for (int ts = 0; ts < 3; ++ts) {
                if (ts >= NTS) continue;
                #pragma unroll
                for (int m = 0; m < 2; ++m)
                    #pragma unroll
                    for (int r = 0; r < 4; ++r)
                        *(_Float16*)((char*)sT + stw_off[ts] + (m * 16 * STR_ + r * STR_) * 2) =
                            (_Float16)res[ts][m][r];
                if (dh == 0 && quad == 0) sk_s[eidx[ts]] = (_Float16)resk[ts][0];
            }
        }
        __syncthreads();   // B1: sT/sk visible; q~(n+1) drained
    }
}

// ---------------- Kernel A+C: intra-chunk attention (f16 MFMA) + merge ----------------
__global__ __launch_bounds__(256) void intra_merge_kernel(
    const _Float16* __restrict__ qh, const _Float16* __restrict__ kh,
    const _Float16* __restrict__ vhT, const float* __restrict__ gse_buf,
    const float* __restrict__ den_buf, const _Float16* __restrict__ part,
    float* __restrict__ out)
{
    const int bid = blockIdx.x;
    const int n = bid & 63, h = (bid >> 6) & 15, b = bid >> 10;
    const int tid = threadIdx.x;
    const int lane = tid & 63, w = tid >> 6;     // 4 waves
    const int nlane = lane & 15, quad = lane >> 4;
    const int t0 = n * CHUNK_;
    const int bh = b * H_ + h;

    __shared__ __align__(16) _Float16 qs[4096];   // q~ [c][d-swz]
    __shared__ __align__(16) _Float16 ksm[4096];  // k~ [m][d-swz]
    __shared__ __align__(16) _Float16 vs[4096];   // v^T [d][c-swz]
    __shared__ __align__(16) _Float16 ss[4096];   // s  [c][m-swz] f16
    __shared__ float nbuf[64 * 68];
    __shared__ float dens[64];

    const size_t obase = (size_t)(bh * NCH_ + n) * 4096;
    gload16(qh + obase + tid * 8, &qs[tid * 8]);
    gload16(qh + obase + 2048 + tid * 8, &qs[2048 + tid * 8]);
    gload16(kh + obase + tid * 8, &ksm[tid * 8]);
    gload16(kh + obase + 2048 + tid * 8, &ksm[2048 + tid * 8]);
    gload16(vhT + obase + tid * 8, &vs[tid * 8]);
    gload16(vhT + obase + 2048 + tid * 8, &vs[2048 + tid * 8]);
    const float gsei = 1.0f / gse_buf[bh * NCH_ + n];
    __syncthreads();

    const int ct = w;
    const int crow = ct * 16 + nlane;
    const int cswz = crow & 7;

    // ======== QK^T: qk~[c][m] = sum_d q~[c][d] k~[m][d]  (16x16x32, K=d)
    floatx4 qk[4];
    #pragma unroll
    for (int mt = 0; mt < 4; ++mt) qk[mt] = (floatx4){0.f, 0.f, 0.f, 0.f};
    #pragma unroll
    for (int ks_ = 0; ks_ < 2; ++ks_) {
        int g = ks_ * 4 + quad;
        half8v a = *(const half8v*)&qs[crow * 64 + ((g ^ cswz) << 3)];
        #pragma unroll
        for (int mt = 0; mt < 4; ++mt) {
            int mrow = mt * 16 + nlane;
            half8v bf = *(const half8v*)&ksm[mrow * 64 + ((g ^ (mrow & 7)) << 3)];
            qk[mt] = __builtin_amdgcn_mfma_f32_16x16x32_f16(a, bf, qk[mt], 0, 0, 0);
        }
    }

    // ======== scores: s = qk~^2 * e^{-gs} * [m<=c]; den row-sum in-register
    float dsum[4] = {0.f, 0.f, 0.f, 0.f};
    #pragma unroll
    for (int mt = 0; mt < 4; ++mt) {
        int m = mt * 16 + nlane;
        #pragma unroll
        for (int r = 0; r < 4; ++r) {
            int c = ct * 16 + quad * 4 + r;
            float sv = qk[mt][r];
            sv = sv * sv * gsei;
            sv = (m <= c) ? sv : 0.f;
            dsum[r] += sv;
            ss[c * 64 + (((m >> 3) ^ (c & 7)) << 3) + (m & 7)] = (_Float16)sv;
        }
    }
    #pragma unroll
    for (int off = 1; off < 16; off <<= 1)
        #pragma unroll
        for (int r = 0; r < 4; ++r) dsum[r] += __shfl_xor(dsum[r], off, 64);
    if (nlane == 0) {
        #pragma unroll
        for (int r = 0; r < 4; ++r) dens[ct * 16 + quad * 4 + r] = dsum[r];
    }
    __syncthreads();   // ss + dens visible (defensive; ss deps are intra-wave)

    // ======== PV: num[c][d] = sum_m s[c][m] v[m][d]  (16x16x32, K=m)
    floatx4 num[4];
    #pragma unroll
    for (int dt = 0; dt < 4; ++dt) num[dt] = (floatx4){0.f, 0.f, 0.f, 0.f};
    #pragma unroll
    for (int ks_ = 0; ks_ < 2; ++ks_) {
        int g = ks_ * 4 + quad;
        half8v a = *(const half8v*)&ss[crow * 64 + ((g ^ cswz) << 3)];
        #pragma unroll
        for (int dt = 0; dt < 4; ++dt) {
            int d = dt * 16 + nlane, dl = d & 31;
            int f = (dl & 7) ^ (dl >> 3);
            half8v bf = *(const half8v*)&vs[d * 64 + ((g ^ f) << 3)];
            num[dt] = __builtin_amdgcn_mfma_f32_16x16x32_f16(a, bf, num[dt], 0, 0, 0);
        }
    }
    #pragma unroll
    for (int dt = 0; dt < 4; ++dt)
        #pragma unroll
        for (int r = 0; r < 4; ++r)
            nbuf[(ct * 16 + quad * 4 + r) * 68 + dt * 16 + nlane] = num[dt][r];
    __syncthreads();

    // ======== tail: add inter parts, divide, store
    for (int idx = tid; idx < 4096; idx += 256) {
        int c = idx >> 6, d = idx & 63;
        float sum = nbuf[c * 68 + d];
        size_t pb = (((size_t)bh * T_ + t0 + c) << 6) + d;
        #pragma unroll
        for (int ehh = 0; ehh < EH_; ++ehh)
            sum += (float)part[(size_t)ehh * OUTN_ + pb];
        float den = dens[c] + den_buf[(size_t)bh * T_ + t0 + c];
        out[((size_t)(b * T_ + t0 + c) * H_ + h) * 64 + d] = sum / fmaxf(den, 1.0f);
    }
}

extern "C" void kernel_launch(void* const* d_in, const int* in_sizes, int n_in,
                              void* d_out, int out_size, void* d_ws, size_t ws_size,
                              hipStream_t stream)
{
    (void)in_sizes; (void)n_in; (void)out_size; (void)ws_size;
    const float* q   = (const float*)d_in[0];
    const float* k   = (const float*)d_in[1];
    const float* v   = (const float*)d_in[2];
    const float* g   = (const float*)d_in[3];
    const float* S0  = (const float*)d_in[4];
    const float* sk0 = (const float*)d_in[5];
    float* out = (float*)d_out;

    // ws: den f32 | part f16 [EH][BHT D] | qh/khT/vhT/kh f16 (16.78MB each) | gse f32
    char* wp = (char*)d_ws;
    float*    den_buf = (float*)wp;                 wp += (size_t)B_ * H_ * T_ * sizeof(float);
    _Float16* part    = (_Float16*)wp;              wp += (size_t)EH_ * OUTN_ * sizeof(_Float16);
    _Float16* qh      = (_Float16*)wp;              wp += (size_t)B_ * H_ * T_ * D_ * sizeof(_Float16);
    _Float16* khT     = (_Float16*)wp;              wp += (size_t)B_ * H_ * T_ * D_ * sizeof(_Float16);
    _Float16* vhT     = (_Float16*)wp;              wp += (size_t)B_ * H_ * T_ * D_ * sizeof(_Float16);
    _Float16* kh      = (_Float16*)wp;              wp += (size_t)B_ * H_ * T_ * D_ * sizeof(_Float16);
    float*    gse_buf = (float*)wp;

    hipMemsetAsync(den_buf, 0, (size_t)B_ * H_ * T_ * sizeof(float), stream);
    prep_kernel<<<dim3(2048), dim3(256), 0, stream>>>(q, k, v, g, qh, kh, khT, vhT, gse_buf);
    scan_kernel<<<dim3(512), dim3(512), 0, stream>>>(qh, khT, vhT, gse_buf, S0, sk0, den_buf, part);
    intra_merge_kernel<<<dim3(2048), dim3(256), 0, stream>>>(qh, kh, vhT, gse_buf, den_buf, part, out);
}

// Round 7
// 500.334 us; speedup vs baseline: 1.0900x; 1.0900x over previous
//
#include <hip/hip_runtime.h>

// Power retention (deg-2), B=2 T=4096 H=16 D=64, CHUNK=64, E=2080.
// Round 10: single-barrier double-buffered scan, as a MECHANICAL delta from
// the proven R8 kernel (533us). All five LDS regions get a [2] buffer dim;
// per chunk: stage(n+1)->[nxt]; MM1 reads qsh/sT/sk[cur]; MM2 reads
// kTs/vTs[cur], writes sT/sk[nxt]; ONE __syncthreads per chunk (drains
// staging vmcnt + orders sT[nxt] vs next chunk's MM1). Wave ownership,
// fragment offsets, part/den writes: R8 VERBATIM (no R7 role-split).
// MM2 skipped at n=63 (never read). prep + MFMA intra_merge unchanged.

#define B_ 2
#define T_ 4096
#define H_ 16
#define D_ 64
#define CHUNK_ 64
#define NCH_ 64
#define E_ 2080
#define EH_ 8
#define NBLK_ 36         // (i, jb) 8-wide blocks per eh-slice (288/8, exact)
#define EPAD_ 288        // NBLK_*8
#define NKS_ 9           // MM1 K-steps of 32
#define STR_ 296         // sT row stride (f16), 592B
#define OUTN_ 8388608    // B*T*H*D

typedef __attribute__((ext_vector_type(8))) _Float16 half8v;
typedef __attribute__((ext_vector_type(4))) float floatx4;

union U8 { half8v h; unsigned u[4]; ushort s[8]; };

static __device__ __forceinline__ float wave_iscan(float g, int lane) {
    #pragma unroll
    for (int off = 1; off < 64; off <<= 1) {
        float o = __shfl_up(g, off, 64);
        if (lane >= off) g += o;
    }
    return g;
}

typedef const __attribute__((address_space(1))) unsigned int* gas1_t;
typedef __attribute__((address_space(3))) unsigned int* las3_t;
static __device__ __forceinline__ void gload16(const void* g, void* l) {
    __builtin_amdgcn_global_load_lds((gas1_t)g, (las3_t)l, 16, 0, 0);
}

// ---------------- Prep: gates + scales + cvt + swizzled transpose ----------------
// qh : [bh][n][c][ ((d>>3) ^ (c&7))*8 + (d&7) ]            q~ = 0.125*exp(0.5*cg)*q
// kh : [bh][n][c][ ((d>>3) ^ (c&7))*8 + (d&7) ]            k~ = exp(0.5*(gs-cg))*k
// khT: [bh][n][d][ ((c>>3) ^ (d&7) ^ (d>>3))*8 + (c&7) ]
// vhT: [bh][n][d][ ((c>>3) ^ (dl&7) ^ (dl>>3))*8 + (c&7) ] dl = d&31 (dh halves)
__global__ __launch_bounds__(256) void prep_kernel(
    const float* __restrict__ q, const float* __restrict__ k, const float* __restrict__ v,
    const float* __restrict__ gate,
    _Float16* __restrict__ qh, _Float16* __restrict__ kh, _Float16* __restrict__ khT,
    _Float16* __restrict__ vhT, float* __restrict__ gse_buf)
{
    const int bid = blockIdx.x;          // bh*64 + n
    const int bh = bid >> 6, n = bid & 63;
    const int b = bh >> 4, h = bh & 15;
    const int t0 = n * CHUNK_;
    const int tid = threadIdx.x;

    __shared__ float cgs[64];
    __shared__ float tbuf[64 * 68];

    if (tid < 64) {
        float g = gate[((size_t)(b * T_ + t0) + tid) * H_ + h];
        cgs[tid] = wave_iscan(g, tid);
    }
    __syncthreads();
    const float gs = cgs[63];
    if (tid == 0) gse_buf[bid] = __expf(gs);

    const int c = tid >> 2, dq = (tid & 3) * 16;
    const size_t gbase = ((size_t)(b * T_ + t0 + c) * H_ + h) * 64 + dq;
    const size_t obase = (size_t)bid * 4096;

    // ---- q~ (no transpose, swizzled d-groups)
    {
        float qsc = 0.125f * __expf(0.5f * cgs[c]);
        #pragma unroll
        for (int g8 = 0; g8 < 2; ++g8) {
            float4 a0 = *(const float4*)(q + gbase + g8 * 8);
            float4 a1 = *(const float4*)(q + gbase + g8 * 8 + 4);
            half8v hv;
            hv[0] = (_Float16)(a0.x * qsc); hv[1] = (_Float16)(a0.y * qsc);
            hv[2] = (_Float16)(a0.z * qsc); hv[3] = (_Float16)(a0.w * qsc);
            hv[4] = (_Float16)(a1.x * qsc); hv[5] = (_Float16)(a1.y * qsc);
            hv[6] = (_Float16)(a1.z * qsc); hv[7] = (_Float16)(a1.w * qsc);
            int grp = (dq >> 3) + g8;
            *(half8v*)&qh[obase + (size_t)(c * 64) + ((grp ^ (c & 7)) << 3)] = hv;
        }
    }
    // ---- k~ -> kh (row-major, q-style swizzle) + LDS [c][d]
    {
        float ksc = __expf(0.5f * (gs - cgs[c]));
        float4 sa[4];
        #pragma unroll
        for (int i = 0; i < 4; ++i) {
            float4 a = *(const float4*)(k + gbase + i * 4);
            sa[i].x = a.x * ksc; sa[i].y = a.y * ksc;
            sa[i].z = a.z * ksc; sa[i].w = a.w * ksc;
            *(float4*)&tbuf[c * 68 + dq + i * 4] = sa[i];
        }
        #pragma unroll
        for (int g8 = 0; g8 < 2; ++g8) {
            half8v hv;
            hv[0] = (_Float16)sa[g8 * 2].x;     hv[1] = (_Float16)sa[g8 * 2].y;
            hv[2] = (_Float16)sa[g8 * 2].z;     hv[3] = (_Float16)sa[g8 * 2].w;
            hv[4] = (_Float16)sa[g8 * 2 + 1].x; hv[5] = (_Float16)sa[g8 * 2 + 1].y;
            hv[6] = (_Float16)sa[g8 * 2 + 1].z; hv[7] = (_Float16)sa[g8 * 2 + 1].w;
            int grp = (dq >> 3) + g8;
            *(half8v*)&kh[obase + (size_t)(c * 64) + ((grp ^ (c & 7)) << 3)] = hv;
        }
    }
    __syncthreads();
    {   // transposed, swizzled store of k~^T
        int d = tid & 63, f = (d & 7) ^ (d >> 3);
        #pragma unroll
        for (int gg = 0; gg < 2; ++gg) {
            int cg = (tid >> 6) * 2 + gg;
            half8v hv;
            #pragma unroll
            for (int j = 0; j < 8; ++j) hv[j] = (_Float16)tbuf[(cg * 8 + j) * 68 + d];
            *(half8v*)&khT[obase + (size_t)(d * 64) + ((cg ^ f) << 3)] = hv;
        }
    }
    __syncthreads();
    {   // v -> LDS (no scale)
        #pragma unroll
        for (int i = 0; i < 4; ++i)
            *(float4*)&tbuf[c * 68 + dq + i * 4] = *(const float4*)(v + gbase + i * 4);
    }
    __syncthreads();
    {   // transposed, swizzled store of v^T (f over dl = d&31)
        int d = tid & 63, dl = d & 31, f = (dl & 7) ^ (dl >> 3);
        #pragma unroll
        for (int gg = 0; gg < 2; ++gg) {
            int cg = (tid >> 6) * 2 + gg;
            half8v hv;
            #pragma unroll
            for (int j = 0; j < 8; ++j) hv[j] = (_Float16)tbuf[(cg * 8 + j) * 68 + d];
            *(half8v*)&vhT[obase + (size_t)(d * 64) + ((cg ^ f) << 3)] = hv;
        }
    }
}

// ---------------- Kernel B: single-barrier double-buffered scan ----------------
__global__ __launch_bounds__(512, 2) void scan_kernel(
    const _Float16* __restrict__ qh, const _Float16* __restrict__ khT,
    const _Float16* __restrict__ vhT, const float* __restrict__ gse_buf,
    const float* __restrict__ S0, const float* __restrict__ sk0,
    float* __restrict__ den_buf, _Float16* __restrict__ part)
{
    const int bid = blockIdx.x;
    // XCD swizzle: all 16 blocks of one bh share bid%8 -> same XCD for q/k/v L2 reuse
    const int bh = (bid & 7) * 4 + (bid >> 7);
    const int inner = (bid >> 3) & 15;
    const int eh = inner & 7, dh = inner >> 3;
    const int tid = threadIdx.x, lane = tid & 63, w = tid >> 6;   // w 0..7
    const int nlane = lane & 15, quad = lane >> 4;

    __shared__ __align__(16) _Float16 sT[2][32 * STR_];  // S^T[d_local][e], 2-bit XOR swz
    __shared__ __align__(16) _Float16 kTs[2][4096];      // k~^T (linear, global-preswizzled)
    __shared__ __align__(16) _Float16 qsh[2][4096];      // q~   (linear, global-preswizzled)
    __shared__ __align__(16) _Float16 vTs[2][2048];      // v^T half (linear, preswizzled)
    __shared__ __align__(16) _Float16 sk_s[2][EPAD_];
    __shared__ int blk_s[NBLK_];                         // i | (jb<<8)

    // ---- build (i, jb) block table for this slice
    for (int t = tid; t < NBLK_; t += 512) {
        int g = eh * NBLK_ + t;
        int i = 0;
        while (g >= 8 - (i >> 3)) { g -= 8 - (i >> 3); ++i; }
        int jb = (i >> 3) + g;
        blk_s[t] = i | (jb << 8);
    }
    __syncthreads();

    const _Float16* qsrc = qh + (size_t)(bh * NCH_) * 4096;
    const _Float16* ksrc = khT + (size_t)(bh * NCH_) * 4096;
    const _Float16* vsrc = vhT + (size_t)(bh * NCH_) * 4096 + dh * 2048;

    // ---- prologue: stage chunk 0 into buffer 0; drains at B0
    gload16(qsrc + tid * 8, &qsh[0][tid * 8]);
    gload16(ksrc + tid * 8, &kTs[0][tid * 8]);
    if (tid < 256) gload16(vsrc + tid * 8, &vTs[0][tid * 8]);

    // ---- sk[0] init (sqrt2 fold; invalid slots stay 0 forever)
    for (int e = tid; e < EPAD_; e += 512) {
        int bv = blk_s[e >> 3];
        int i = bv & 255, j8 = (bv >> 8) * 8 + (e & 7);
        float sv = 0.f;
        if (j8 >= i) {
            int er = (i * (129 - i)) / 2 + (j8 - i);
            float coef = (j8 == i) ? 1.f : 1.41421356237f;
            sv = sk0[(size_t)bh * E_ + er] * coef;
        }
        sk_s[0][e] = (_Float16)sv;
    }
    // ---- sT[0] init (f16 copy of S-hat = coef * S0), 2-bit XOR swizzled columns
    for (int p = tid; p < 32 * EPAD_; p += 512) {
        int dl = p / EPAD_;
        int e = p - dl * EPAD_;
        int bv = blk_s[e >> 3];
        int i = bv & 255, j8 = (bv >> 8) * 8 + (e & 7);
        float sv = 0.f;
        if (j8 >= i) {
            int er = (i * (129 - i)) / 2 + (j8 - i);
            float coef = (j8 == i) ? 1.f : 1.41421356237f;
            sv = S0[((size_t)bh * E_ + er) * 64 + dh * 32 + dl] * coef;
        }
        int col8 = e >> 3, gsw = (dl >> 2) & 3;
        int pc = ((col8 & ~3) | ((col8 & 3) ^ gsw)) * 8 + (e & 7);
        sT[0][dl * STR_ + pc] = (_Float16)sv;
    }

    // ---- wave roles (R8 verbatim): wave (mt, nt0); all 8 do MM1 and MM2
    const int mt = w & 3, nt0 = w >> 2;
    const int c_row = mt * 16 + nlane;
    const bool den_w = (w < 4) && (dh == 0);
    const int NTS = (w < 2) ? 3 : 2;          // MM2: waves 0,1 own a 3rd tile (16,17)

    // ---- resident S fragments: wave owns tiles {w, w+8, (w+16 if w<2)} x mtv{0,1}(+sk)
    floatx4 res[3][2];
    floatx4 resk[3];
    #pragma unroll
    for (int ts = 0; ts < 3; ++ts) {
        res[ts][0] = (floatx4){0.f, 0.f, 0.f, 0.f};
        res[ts][1] = (floatx4){0.f, 0.f, 0.f, 0.f};
        resk[ts]   = (floatx4){0.f, 0.f, 0.f, 0.f};
        if (ts >= NTS) continue;
        int tile = w + 8 * ts;
        int e = tile * 16 + nlane;
        int bv = blk_s[e >> 3];
        int i = bv & 255, j8 = (bv >> 8) * 8 + (e & 7);
        if (j8 >= i) {
            int er = (i * (129 - i)) / 2 + (j8 - i);
            float coef = (j8 == i) ? 1.f : 1.41421356237f;
            #pragma unroll
            for (int m = 0; m < 2; ++m) {
                floatx4 t4 = *(const floatx4*)&S0[((size_t)bh * E_ + er) * 64 + dh * 32 + m * 16 + quad * 4];
                #pragma unroll
                for (int r = 0; r < 4; ++r) res[ts][m][r] = t4[r] * coef;
            }
            if (dh == 0 && quad == 0) resk[ts][0] = sk0[(size_t)bh * E_ + er] * coef;
        }
    }

    // ---- chunk-invariant MM1 addresses (byte offsets, within-buffer)
    int qiu_off[NKS_], qrow_off[NKS_];
    #pragma unroll
    for (int ks = 0; ks < NKS_; ++ks) {
        int bv = blk_s[ks * 4 + quad];
        int ib = bv & 255, jb = bv >> 8;
        qiu_off[ks]  = (c_row * 64 + (((ib >> 3) ^ (c_row & 7)) << 3) + (ib & 7)) * 2;
        qrow_off[ks] = (c_row * 64 + ((jb ^ (c_row & 7)) << 3)) * 2;
    }
    const int b0_off = ((nt0 * 16 + nlane) * STR_ + ((quad ^ ((nlane >> 2) & 3)) << 3)) * 2;

    // ---- chunk-invariant MM2 addresses + m2 splats (R8 verbatim)
    int pa_off[3], pb_off[3], stw_off[3], eidx[3];
    unsigned m2sp[3];
    #pragma unroll
    for (int ts = 0; ts < 3; ++ts) {
        pa_off[ts] = pb_off[ts] = stw_off[ts] = eidx[ts] = 0; m2sp[ts] = 0;
        if (ts >= NTS) continue;
        int tile = w + 8 * ts, e = tile * 16 + nlane;
        int bv = blk_s[e >> 3];
        int ib = bv & 255, j8 = (bv >> 8) * 8 + (e & 7);
        int fib = (ib & 7) ^ (ib >> 3), fj8 = (j8 & 7) ^ (j8 >> 3);
        pa_off[ts] = (ib * 64 + ((quad ^ fib) << 3)) * 2;
        pb_off[ts] = (j8 * 64 + ((quad ^ fj8) << 3)) * 2;
        int col8 = e >> 3;
        int pc = ((col8 & ~3) | ((col8 & 3) ^ quad)) * 8 + (e & 7);
        stw_off[ts] = (quad * 4 * STR_ + pc) * 2;
        eidx[ts] = e;
        unsigned hv = (j8 < ib) ? 0u : ((j8 == ib) ? 0x3C00u : 0x4000u);  // {0,1,2} coef^2
        m2sp[ts] = (hv << 16) | hv;
    }
    int af_off[2];
    #pragma unroll
    for (int m = 0; m < 2; ++m) {
        int row = m * 16 + nlane;
        int fr = (row & 7) ^ (row >> 3);
        af_off[m] = (row * 64 + ((quad ^ fr) << 3)) * 2;
    }
    half8v af_sk = (half8v){0, 0, 0, 0, 0, 0, 0, 0};
    if (nlane == 0) af_sk = (half8v){1, 1, 1, 1, 1, 1, 1, 1};

    _Float16* ppart = part + (size_t)eh * OUTN_ + (((size_t)bh * T_) << 6) + dh * 32 + nt0 * 16 + nlane;

    __syncthreads();   // B0: init done; chunk-0 staging drained

    for (int n = 0; n < NCH_; ++n) {
        const int cur = n & 1, nxt = cur ^ 1;

        // ---- stage chunk n+1 into [nxt]; drains at this chunk's barrier
        if (n + 1 < NCH_) {
            gload16(qsrc + (size_t)(n + 1) * 4096 + tid * 8, &qsh[nxt][tid * 8]);
            gload16(ksrc + (size_t)(n + 1) * 4096 + tid * 8, &kTs[nxt][tid * 8]);
            if (tid < 256) gload16(vsrc + (size_t)(n + 1) * 4096 + tid * 8, &vTs[nxt][tid * 8]);
        }
        const float gsev = gse_buf[bh * NCH_ + n];

        // ======== MM1: num[c][d] = pq . S-hat(n) from [cur]; den rides with sk
        {
            const char* qb = (const char*)&qsh[cur][0];
            const char* sb = (const char*)&sT[cur][0];
            floatx4 acc0 = {0.f, 0.f, 0.f, 0.f};
            floatx4 acc1 = {0.f, 0.f, 0.f, 0.f};
            #pragma unroll
            for (int ks = 0; ks < NKS_; ++ks) {
                ushort qiu = *(const ushort*)(qb + qiu_off[ks]);
                unsigned qi2 = ((unsigned)qiu << 16) | qiu;
                U8 qv; qv.u[0] = qi2; qv.u[1] = qi2; qv.u[2] = qi2; qv.u[3] = qi2;
                half8v qrow = *(const half8v*)(qb + qrow_off[ks]);
                half8v afr = qv.h * qrow;            // no m8: invalid sT cols are 0
                half8v b0 = *(const half8v*)(sb + b0_off + ks * 64);
                acc0 = __builtin_amdgcn_mfma_f32_16x16x32_f16(afr, b0, acc0, 0, 0, 0);
                if (den_w) {
                    half8v b1 = (half8v){0, 0, 0, 0, 0, 0, 0, 0};
                    if (nlane == 0) b1 = *(const half8v*)&sk_s[cur][ks * 32 + quad * 8];
                    acc1 = __builtin_amdgcn_mfma_f32_16x16x32_f16(afr, b1, acc1, 0, 0, 0);
                }
            }
            _Float16* pp = ppart + ((size_t)(n * CHUNK_ + mt * 16 + quad * 4) << 6);
            #pragma unroll
            for (int r = 0; r < 4; ++r) pp[(size_t)r << 6] = (_Float16)acc0[r];
            if (den_w && nlane == 0) {
                #pragma unroll
                for (int r = 0; r < 4; ++r)
                    atomicAdd(&den_buf[(size_t)bh * T_ + n * CHUNK_ + mt * 16 + quad * 4 + r], acc1[r]);
            }
        }

        // ======== MM2: S-hat(n+1) = gse*S-hat(n) + v^T.pk from [cur] -> sT[nxt]
        //          (skipped at n=63: never read)
        if (n < NCH_ - 1) {
            const char* kb = (const char*)&kTs[cur][0];
            const char* vb = (const char*)&vTs[cur][0];
            #pragma unroll
            for (int ts = 0; ts < 3; ++ts) {
                if (ts >= NTS) continue;
                #pragma unroll
                for (int m = 0; m < 2; ++m)
                    #pragma unroll
                    for (int r = 0; r < 4; ++r) res[ts][m][r] *= gsev;
                if (dh == 0) resk[ts][0] *= gsev;
            }
            #pragma unroll
            for (int k2 = 0; k2 < 2; ++k2) {
                const int xo = k2 * 64;    // c-group bit2 flip == byte bit6 flip
                half8v af0 = *(const half8v*)(vb + (af_off[0] ^ xo));
                half8v af1 = *(const half8v*)(vb + (af_off[1] ^ xo));
                #pragma unroll
                for (int ts = 0; ts < 3; ++ts) {
                    if (ts >= NTS) continue;
                    half8v pa = *(const half8v*)(kb + (pa_off[ts] ^ xo));
                    half8v pb = *(const half8v*)(kb + (pb_off[ts] ^ xo));
                    U8 mv; mv.u[0] = m2sp[ts]; mv.u[1] = m2sp[ts]; mv.u[2] = m2sp[ts]; mv.u[3] = m2sp[ts];
                    half8v bfr = pa * pb * mv.h;
                    res[ts][0] = __builtin_amdgcn_mfma_f32_16x16x32_f16(af0, bfr, res[ts][0], 0, 0, 0);
                    res[ts][1] = __builtin_amdgcn_mfma_f32_16x16x32_f16(af1, bfr, res[ts][1], 0, 0, 0);
                    if (dh == 0)
                        resk[ts] = __builtin_amdgcn_mfma_f32_16x16x32_f16(af_sk, bfr, resk[ts], 0, 0, 0);
                }
            }
            // write back S-hat(n+1) into sT[nxt] (swizzled, 2-way max) + sk[nxt]
            char* stb = (char*)&sT[nxt][0];
            #pragma unroll
            for (int ts = 0; ts < 3; ++ts) {
                if (ts >= NTS) continue;
                #pragma unroll
                for (int m = 0; m < 2; ++m)
                    #pragma unroll
                    for (int r = 0; r < 4; ++r)
                        *(_Float16*)(stb + stw_off[ts] + (m * 16 * STR_ + r * STR_) * 2) =
                            (_Float16)res[ts][m][r];
                if (dh == 0 && quad == 0) sk_s[nxt][eidx[ts]] = (_Float16)resk[ts][0];
            }
        }

        __syncthreads();   // single barrier: staging drained; sT/sk[nxt] visible
    }
}

// ---------------- Kernel A+C: intra-chunk attention (f16 MFMA) + merge ----------------
__global__ __launch_bounds__(256) void intra_merge_kernel(
    const _Float16* __restrict__ qh, const _Float16* __restrict__ kh,
    const _Float16* __restrict__ vhT, const float* __restrict__ gse_buf,
    const float* __restrict__ den_buf, const _Float16* __restrict__ part,
    float* __restrict__ out)
{
    const int bid = blockIdx.x;
    const int n = bid & 63, h = (bid >> 6) & 15, b = bid >> 10;
    const int tid = threadIdx.x;
    const int lane = tid & 63, w = tid >> 6;     // 4 waves
    const int nlane = lane & 15, quad = lane >> 4;
    const int t0 = n * CHUNK_;
    const int bh = b * H_ + h;

    __shared__ __align__(16) _Float16 qs[4096];   // q~ [c][d-swz]
    __shared__ __align__(16) _Float16 ksm[4096];  // k~ [m][d-swz]
    __shared__ __align__(16) _Float16 vs[4096];   // v^T [d][c-swz]
    __shared__ __align__(16) _Float16 ss[4096];   // s  [c][m-swz] f16
    __shared__ float nbuf[64 * 68];
    __shared__ float dens[64];

    const size_t obase = (size_t)(bh * NCH_ + n) * 4096;
    gload16(qh + obase + tid * 8, &qs[tid * 8]);
    gload16(qh + obase + 2048 + tid * 8, &qs[2048 + tid * 8]);
    gload16(kh + obase + tid * 8, &ksm[tid * 8]);
    gload16(kh + obase + 2048 + tid * 8, &ksm[2048 + tid * 8]);
    gload16(vhT + obase + tid * 8, &vs[tid * 8]);
    gload16(vhT + obase + 2048 + tid * 8, &vs[2048 + tid * 8]);
    const float gsei = 1.0f / gse_buf[bh * NCH_ + n];
    __syncthreads();

    const int ct = w;
    const int crow = ct * 16 + nlane;
    const int cswz = crow & 7;

    // ======== QK^T: qk~[c][m] = sum_d q~[c][d] k~[m][d]  (16x16x32, K=d)
    floatx4 qk[4];
    #pragma unroll
    for (int mt = 0; mt < 4; ++mt) qk[mt] = (floatx4){0.f, 0.f, 0.f, 0.f};
    #pragma unroll
    for (int ks_ = 0; ks_ < 2; ++ks_) {
        int g = ks_ * 4 + quad;
        half8v a = *(const half8v*)&qs[crow * 64 + ((g ^ cswz) << 3)];
        #pragma unroll
        for (int mt = 0; mt < 4; ++mt) {
            int mrow = mt * 16 + nlane;
            half8v bf = *(const half8v*)&ksm[mrow * 64 + ((g ^ (mrow & 7)) << 3)];
            qk[mt] = __builtin_amdgcn_mfma_f32_16x16x32_f16(a, bf, qk[mt], 0, 0, 0);
        }
    }

    // ======== scores: s = qk~^2 * e^{-gs} * [m<=c]; den row-sum in-register
    float dsum[4] = {0.f, 0.f, 0.f, 0.f};
    #pragma unroll
    for (int mt = 0; mt < 4; ++mt) {
        int m = mt * 16 + nlane;
        #pragma unroll
        for (int r = 0; r < 4; ++r) {
            int c = ct * 16 + quad * 4 + r;
            float sv = qk[mt][r];
            sv = sv * sv * gsei;
            sv = (m <= c) ? sv : 0.f;
            dsum[r] += sv;
            ss[c * 64 + (((m >> 3) ^ (c & 7)) << 3) + (m & 7)] = (_Float16)sv;
        }
    }
    #pragma unroll
    for (int off = 1; off < 16; off <<= 1)
        #pragma unroll
        for (int r = 0; r < 4; ++r) dsum[r] += __shfl_xor(dsum[r], off, 64);
    if (nlane == 0) {
        #pragma unroll
        for (int r = 0; r < 4; ++r) dens[ct * 16 + quad * 4 + r] = dsum[r];
    }
    __syncthreads();   // ss + dens visible (defensive; ss deps are intra-wave)

    // ======== PV: num[c][d] = sum_m s[c][m] v[m][d]  (16x16x32, K=m)
    floatx4 num[4];
    #pragma unroll
    for (int dt = 0; dt < 4; ++dt) num[dt] = (floatx4){0.f, 0.f, 0.f, 0.f};
    #pragma unroll
    for (int ks_ = 0; ks_ < 2; ++ks_) {
        int g = ks_ * 4 + quad;
        half8v a = *(const half8v*)&ss[crow * 64 + ((g ^ cswz) << 3)];
        #pragma unroll
        for (int dt = 0; dt < 4; ++dt) {
            int d = dt * 16 + nlane, dl = d & 31;
            int f = (dl & 7) ^ (dl >> 3);
            half8v bf = *(const half8v*)&vs[d * 64 + ((g ^ f) << 3)];
            num[dt] = __builtin_amdgcn_mfma_f32_16x16x32_f16(a, bf, num[dt], 0, 0, 0);
        }
    }
    #pragma unroll
    for (int dt = 0; dt < 4; ++dt)
        #pragma unroll
        for (int r = 0; r < 4; ++r)
            nbuf[(ct * 16 + quad * 4 + r) * 68 + dt * 16 + nlane] = num[dt][r];
    __syncthreads();

    // ======== tail: add inter parts, divide, store
    for (int idx = tid; idx < 4096; idx += 256) {
        int c = idx >> 6, d = idx & 63;
        float sum = nbuf[c * 68 + d];
        size_t pb = (((size_t)bh * T_ + t0 + c) << 6) + d;
        #pragma unroll
        for (int ehh = 0; ehh < EH_; ++ehh)
            sum += (float)part[(size_t)ehh * OUTN_ + pb];
        float den = dens[c] + den_buf[(size_t)bh * T_ + t0 + c];
        out[((size_t)(b * T_ + t0 + c) * H_ + h) * 64 + d] = sum / fmaxf(den, 1.0f);
    }
}

extern "C" void kernel_launch(void* const* d_in, const int* in_sizes, int n_in,
                              void* d_out, int out_size, void* d_ws, size_t ws_size,
                              hipStream_t stream)
{
    (void)in_sizes; (void)n_in; (void)out_size; (void)ws_size;
    const float* q   = (const float*)d_in[0];
    const float* k   = (const float*)d_in[1];
    const float* v   = (const float*)d_in[2];
    const float* g   = (const float*)d_in[3];
    const float* S0  = (const float*)d_in[4];
    const float* sk0 = (const float*)d_in[5];
    float* out = (float*)d_out;

    // ws: den f32 | part f16 [EH][BHT D] | qh/khT/vhT/kh f16 (16.78MB each) | gse f32
    char* wp = (char*)d_ws;
    float*    den_buf = (float*)wp;                 wp += (size_t)B_ * H_ * T_ * sizeof(float);
    _Float16* part    = (_Float16*)wp;              wp += (size_t)EH_ * OUTN_ * sizeof(_Float16);
    _Float16* qh      = (_Float16*)wp;              wp += (size_t)B_ * H_ * T_ * D_ * sizeof(_Float16);
    _Float16* khT     = (_Float16*)wp;              wp += (size_t)B_ * H_ * T_ * D_ * sizeof(_Float16);
    _Float16* vhT     = (_Float16*)wp;              wp += (size_t)B_ * H_ * T_ * D_ * sizeof(_Float16);
    _Float16* kh      = (_Float16*)wp;              wp += (size_t)B_ * H_ * T_ * D_ * sizeof(_Float16);
    float*    gse_buf = (float*)wp;

    hipMemsetAsync(den_buf, 0, (size_t)B_ * H_ * T_ * sizeof(float), stream);
    prep_kernel<<<dim3(2048), dim3(256), 0, stream>>>(q, k, v, g, qh, kh, khT, vhT, gse_buf);
    scan_kernel<<<dim3(512), dim3(512), 0, stream>>>(qh, khT, vhT, gse_buf, S0, sk0, den_buf, part);
    intra_merge_kernel<<<dim3(2048), dim3(256), 0, stream>>>(qh, kh, vhT, gse_buf, den_buf, part, out);
}

// Round 8
// 401.791 us; speedup vs baseline: 1.3573x; 1.2453x over previous
//
#include <hip/hip_runtime.h>

// Power retention (deg-2), B=2 T=4096 H=16 D=64, CHUNK=64, E=2080.
// Round 11: dh-merged scan (grid 256 = bh32 x eh8, full d=64 per block),
// single-barrier double-buffered structure from R10 kept verbatim.
// Rationale: the dh=0/dh=1 blocks duplicated all MM2 bfr builds (kTs reads
// + pk VALU), all MM1 afr reads, and the kTs/qsh staging. Merging halves
// that traffic (~30% of scan LDS bytes) at the cost of sT dbuf 76KB ->
// 126KB total LDS (1 block/CU, which R10 already was per occupancy=21.6).
// prep + intra_merge unchanged from R10.

#define B_ 2
#define T_ 4096
#define H_ 16
#define D_ 64
#define CHUNK_ 64
#define NCH_ 64
#define E_ 2080
#define EH_ 8
#define NBLK_ 36         // (i, jb) 8-wide blocks per eh-slice (288/8, exact)
#define EPAD_ 288        // NBLK_*8
#define NKS_ 9           // MM1 K-steps of 32
#define STR_ 296         // sT row stride (f16), 592B
#define OUTN_ 8388608    // B*T*H*D

typedef __attribute__((ext_vector_type(8))) _Float16 half8v;
typedef __attribute__((ext_vector_type(4))) float floatx4;

union U8 { half8v h; unsigned u[4]; ushort s[8]; };

static __device__ __forceinline__ float wave_iscan(float g, int lane) {
    #pragma unroll
    for (int off = 1; off < 64; off <<= 1) {
        float o = __shfl_up(g, off, 64);
        if (lane >= off) g += o;
    }
    return g;
}

typedef const __attribute__((address_space(1))) unsigned int* gas1_t;
typedef __attribute__((address_space(3))) unsigned int* las3_t;
static __device__ __forceinline__ void gload16(const void* g, void* l) {
    __builtin_amdgcn_global_load_lds((gas1_t)g, (las3_t)l, 16, 0, 0);
}

// ---------------- Prep: gates + scales + cvt + swizzled transpose ----------------
// qh : [bh][n][c][ ((d>>3) ^ (c&7))*8 + (d&7) ]            q~ = 0.125*exp(0.5*cg)*q
// kh : [bh][n][c][ ((d>>3) ^ (c&7))*8 + (d&7) ]            k~ = exp(0.5*(gs-cg))*k
// khT: [bh][n][d][ ((c>>3) ^ (d&7) ^ (d>>3))*8 + (c&7) ]
// vhT: [bh][n][d][ ((c>>3) ^ (dl&7) ^ (dl>>3))*8 + (c&7) ] dl = d&31
__global__ __launch_bounds__(256) void prep_kernel(
    const float* __restrict__ q, const float* __restrict__ k, const float* __restrict__ v,
    const float* __restrict__ gate,
    _Float16* __restrict__ qh, _Float16* __restrict__ kh, _Float16* __restrict__ khT,
    _Float16* __restrict__ vhT, float* __restrict__ gse_buf)
{
    const int bid = blockIdx.x;          // bh*64 + n
    const int bh = bid >> 6, n = bid & 63;
    const int b = bh >> 4, h = bh & 15;
    const int t0 = n * CHUNK_;
    const int tid = threadIdx.x;

    __shared__ float cgs[64];
    __shared__ float tbuf[64 * 68];

    if (tid < 64) {
        float g = gate[((size_t)(b * T_ + t0) + tid) * H_ + h];
        cgs[tid] = wave_iscan(g, tid);
    }
    __syncthreads();
    const float gs = cgs[63];
    if (tid == 0) gse_buf[bid] = __expf(gs);

    const int c = tid >> 2, dq = (tid & 3) * 16;
    const size_t gbase = ((size_t)(b * T_ + t0 + c) * H_ + h) * 64 + dq;
    const size_t obase = (size_t)bid * 4096;

    // ---- q~ (no transpose, swizzled d-groups)
    {
        float qsc = 0.125f * __expf(0.5f * cgs[c]);
        #pragma unroll
        for (int g8 = 0; g8 < 2; ++g8) {
            float4 a0 = *(const float4*)(q + gbase + g8 * 8);
            float4 a1 = *(const float4*)(q + gbase + g8 * 8 + 4);
            half8v hv;
            hv[0] = (_Float16)(a0.x * qsc); hv[1] = (_Float16)(a0.y * qsc);
            hv[2] = (_Float16)(a0.z * qsc); hv[3] = (_Float16)(a0.w * qsc);
            hv[4] = (_Float16)(a1.x * qsc); hv[5] = (_Float16)(a1.y * qsc);
            hv[6] = (_Float16)(a1.z * qsc); hv[7] = (_Float16)(a1.w * qsc);
            int grp = (dq >> 3) + g8;
            *(half8v*)&qh[obase + (size_t)(c * 64) + ((grp ^ (c & 7)) << 3)] = hv;
        }
    }
    // ---- k~ -> kh (row-major, q-style swizzle) + LDS [c][d]
    {
        float ksc = __expf(0.5f * (gs - cgs[c]));
        float4 sa[4];
        #pragma unroll
        for (int i = 0; i < 4; ++i) {
            float4 a = *(const float4*)(k + gbase + i * 4);
            sa[i].x = a.x * ksc; sa[i].y = a.y * ksc;
            sa[i].z = a.z * ksc; sa[i].w = a.w * ksc;
            *(float4*)&tbuf[c * 68 + dq + i * 4] = sa[i];
        }
        #pragma unroll
        for (int g8 = 0; g8 < 2; ++g8) {
            half8v hv;
            hv[0] = (_Float16)sa[g8 * 2].x;     hv[1] = (_Float16)sa[g8 * 2].y;
            hv[2] = (_Float16)sa[g8 * 2].z;     hv[3] = (_Float16)sa[g8 * 2].w;
            hv[4] = (_Float16)sa[g8 * 2 + 1].x; hv[5] = (_Float16)sa[g8 * 2 + 1].y;
            hv[6] = (_Float16)sa[g8 * 2 + 1].z; hv[7] = (_Float16)sa[g8 * 2 + 1].w;
            int grp = (dq >> 3) + g8;
            *(half8v*)&kh[obase + (size_t)(c * 64) + ((grp ^ (c & 7)) << 3)] = hv;
        }
    }
    __syncthreads();
    {   // transposed, swizzled store of k~^T
        int d = tid & 63, f = (d & 7) ^ (d >> 3);
        #pragma unroll
        for (int gg = 0; gg < 2; ++gg) {
            int cg = (tid >> 6) * 2 + gg;
            half8v hv;
            #pragma unroll
            for (int j = 0; j < 8; ++j) hv[j] = (_Float16)tbuf[(cg * 8 + j) * 68 + d];
            *(half8v*)&khT[obase + (size_t)(d * 64) + ((cg ^ f) << 3)] = hv;
        }
    }
    __syncthreads();
    {   // v -> LDS (no scale)
        #pragma unroll
        for (int i = 0; i < 4; ++i)
            *(float4*)&tbuf[c * 68 + dq + i * 4] = *(const float4*)(v + gbase + i * 4);
    }
    __syncthreads();
    {   // transposed, swizzled store of v^T (f over dl = d&31)
        int d = tid & 63, dl = d & 31, f = (dl & 7) ^ (dl >> 3);
        #pragma unroll
        for (int gg = 0; gg < 2; ++gg) {
            int cg = (tid >> 6) * 2 + gg;
            half8v hv;
            #pragma unroll
            for (int j = 0; j < 8; ++j) hv[j] = (_Float16)tbuf[(cg * 8 + j) * 68 + d];
            *(half8v*)&vhT[obase + (size_t)(d * 64) + ((cg ^ f) << 3)] = hv;
        }
    }
}

// ---------------- Kernel B: dh-merged single-barrier double-buffered scan ----------------
__global__ __launch_bounds__(512, 2) void scan_kernel(
    const _Float16* __restrict__ qh, const _Float16* __restrict__ khT,
    const _Float16* __restrict__ vhT, const float* __restrict__ gse_buf,
    const float* __restrict__ S0, const float* __restrict__ sk0,
    float* __restrict__ den_buf, _Float16* __restrict__ part)
{
    const int bid = blockIdx.x;          // 256 blocks
    // XCD swizzle: all 8 eh-blocks of one bh share bid&7 -> same XCD
    const int bh = (bid & 7) * 4 + (bid >> 6);
    const int eh = (bid >> 3) & 7;
    const int tid = threadIdx.x, lane = tid & 63, w = tid >> 6;   // w 0..7
    const int nlane = lane & 15, quad = lane >> 4;

    __shared__ __align__(16) _Float16 sT[2][64 * STR_]; // S^T[d][e], 2-bit XOR swz, 75.8KB
    __shared__ __align__(16) _Float16 kTs[2][4096];     // k~^T (linear, global-preswizzled)
    __shared__ __align__(16) _Float16 qsh[2][4096];     // q~   (linear, global-preswizzled)
    __shared__ __align__(16) _Float16 vTs[2][4096];     // v^T full d (linear, preswizzled)
    __shared__ __align__(16) _Float16 sk_s[2][EPAD_];
    __shared__ int blk_s[NBLK_];                        // i | (jb<<8)

    // ---- build (i, jb) block table for this slice
    for (int t = tid; t < NBLK_; t += 512) {
        int g = eh * NBLK_ + t;
        int i = 0;
        while (g >= 8 - (i >> 3)) { g -= 8 - (i >> 3); ++i; }
        int jb = (i >> 3) + g;
        blk_s[t] = i | (jb << 8);
    }
    __syncthreads();

    const _Float16* qsrc = qh + (size_t)(bh * NCH_) * 4096;
    const _Float16* ksrc = khT + (size_t)(bh * NCH_) * 4096;
    const _Float16* vsrc = vhT + (size_t)(bh * NCH_) * 4096;

    // ---- prologue: stage chunk 0 into buffer 0; drains at B0
    gload16(qsrc + tid * 8, &qsh[0][tid * 8]);
    gload16(ksrc + tid * 8, &kTs[0][tid * 8]);
    gload16(vsrc + tid * 8, &vTs[0][tid * 8]);

    // ---- sk[0] init (sqrt2 fold; invalid slots stay 0 forever)
    for (int e = tid; e < EPAD_; e += 512) {
        int bv = blk_s[e >> 3];
        int i = bv & 255, j8 = (bv >> 8) * 8 + (e & 7);
        float sv = 0.f;
        if (j8 >= i) {
            int er = (i * (129 - i)) / 2 + (j8 - i);
            float coef = (j8 == i) ? 1.f : 1.41421356237f;
            sv = sk0[(size_t)bh * E_ + er] * coef;
        }
        sk_s[0][e] = (_Float16)sv;
    }
    // ---- sT[0] init (f16 copy of S-hat = coef * S0), 2-bit XOR swizzled columns
    for (int p = tid; p < 64 * EPAD_; p += 512) {
        int d = p / EPAD_;
        int e = p - d * EPAD_;
        int bv = blk_s[e >> 3];
        int i = bv & 255, j8 = (bv >> 8) * 8 + (e & 7);
        float sv = 0.f;
        if (j8 >= i) {
            int er = (i * (129 - i)) / 2 + (j8 - i);
            float coef = (j8 == i) ? 1.f : 1.41421356237f;
            sv = S0[((size_t)bh * E_ + er) * 64 + d] * coef;
        }
        int col8 = e >> 3, gsw = (d >> 2) & 3;
        int pc = ((col8 & ~3) | ((col8 & 3) ^ gsw)) * 8 + (e & 7);
        sT[0][d * STR_ + pc] = (_Float16)sv;
    }

    // ---- wave roles: MM1 wave (mt = w&3, nth = w>>2 covering d-cols nth*32..+31);
    //      MM2 wave owns tiles {w, w+8, (w+16 if w<2)} x m 0..3 (+sk)
    const int mt = w & 3, nth = w >> 2;
    const int c_row = mt * 16 + nlane;
    const bool den_w = (w < 4);
    const int NTS = (w < 2) ? 3 : 2;

    // ---- resident S fragments
    floatx4 res[3][4];
    floatx4 resk[3];
    #pragma unroll
    for (int ts = 0; ts < 3; ++ts) {
        #pragma unroll
        for (int m = 0; m < 4; ++m) res[ts][m] = (floatx4){0.f, 0.f, 0.f, 0.f};
        resk[ts] = (floatx4){0.f, 0.f, 0.f, 0.f};
        if (ts >= NTS) continue;
        int tile = w + 8 * ts;
        int e = tile * 16 + nlane;
        int bv = blk_s[e >> 3];
        int i = bv & 255, j8 = (bv >> 8) * 8 + (e & 7);
        if (j8 >= i) {
            int er = (i * (129 - i)) / 2 + (j8 - i);
            float coef = (j8 == i) ? 1.f : 1.41421356237f;
            #pragma unroll
            for (int m = 0; m < 4; ++m) {
                floatx4 t4 = *(const floatx4*)&S0[((size_t)bh * E_ + er) * 64 + m * 16 + quad * 4];
                #pragma unroll
                for (int r = 0; r < 4; ++r) res[ts][m][r] = t4[r] * coef;
            }
            if (quad == 0) resk[ts][0] = sk0[(size_t)bh * E_ + er] * coef;
        }
    }

    // ---- chunk-invariant MM1 addresses (byte offsets, within-buffer)
    int qiu_off[NKS_], qrow_off[NKS_];
    #pragma unroll
    for (int ks = 0; ks < NKS_; ++ks) {
        int bv = blk_s[ks * 4 + quad];
        int ib = bv & 255, jb = bv >> 8;
        qiu_off[ks]  = (c_row * 64 + (((ib >> 3) ^ (c_row & 7)) << 3) + (ib & 7)) * 2;
        qrow_off[ks] = (c_row * 64 + ((jb ^ (c_row & 7)) << 3)) * 2;
    }
    const int swzb = (quad ^ ((nlane >> 2) & 3)) << 3;
    const int b0o0 = ((nth * 32 + nlane) * STR_ + swzb) * 2;
    const int b0o1 = ((nth * 32 + 16 + nlane) * STR_ + swzb) * 2;

    // ---- chunk-invariant MM2 addresses + m2 splats
    int pa_off[3], pb_off[3], stw_off[3], eidx[3];
    unsigned m2sp[3];
    #pragma unroll
    for (int ts = 0; ts < 3; ++ts) {
        pa_off[ts] = pb_off[ts] = stw_off[ts] = eidx[ts] = 0; m2sp[ts] = 0;
        if (ts >= NTS) continue;
        int tile = w + 8 * ts, e = tile * 16 + nlane;
        int bv = blk_s[e >> 3];
        int ib = bv & 255, j8 = (bv >> 8) * 8 + (e & 7);
        int fib = (ib & 7) ^ (ib >> 3), fj8 = (j8 & 7) ^ (j8 >> 3);
        pa_off[ts] = (ib * 64 + ((quad ^ fib) << 3)) * 2;
        pb_off[ts] = (j8 * 64 + ((quad ^ fj8) << 3)) * 2;
        int col8 = e >> 3;
        int pc = ((col8 & ~3) | ((col8 & 3) ^ quad)) * 8 + (e & 7);
        stw_off[ts] = (quad * 4 * STR_ + pc) * 2;
        eidx[ts] = e;
        unsigned hv = (j8 < ib) ? 0u : ((j8 == ib) ? 0x3C00u : 0x4000u);  // {0,1,2} coef^2
        m2sp[ts] = (hv << 16) | hv;
    }
    int af_off[4];
    #pragma unroll
    for (int m = 0; m < 4; ++m) {
        int row = m * 16 + nlane, dl = row & 31;
        int fr = (dl & 7) ^ (dl >> 3);
        af_off[m] = (row * 64 + ((quad ^ fr) << 3)) * 2;
    }
    half8v af_sk = (half8v){0, 0, 0, 0, 0, 0, 0, 0};
    if (nlane == 0) af_sk = (half8v){1, 1, 1, 1, 1, 1, 1, 1};

    _Float16* ppart = part + (size_t)eh * OUTN_ + (((size_t)bh * T_) << 6) + nth * 32 + nlane;

    __syncthreads();   // B0: init done; chunk-0 staging drained

    for (int n = 0; n < NCH_; ++n) {
        const int cur = n & 1, nxt = cur ^ 1;

        // ---- stage chunk n+1 into [nxt]; drains at this chunk's barrier
        if (n + 1 < NCH_) {
            gload16(qsrc + (size_t)(n + 1) * 4096 + tid * 8, &qsh[nxt][tid * 8]);
            gload16(ksrc + (size_t)(n + 1) * 4096 + tid * 8, &kTs[nxt][tid * 8]);
            gload16(vsrc + (size_t)(n + 1) * 4096 + tid * 8, &vTs[nxt][tid * 8]);
        }
        const float gsev = gse_buf[bh * NCH_ + n];

        // ======== MM1: num[c][d] = pq . S-hat(n), d-cols nth*32..+31; den rides
        {
            const char* qb = (const char*)&qsh[cur][0];
            const char* sb = (const char*)&sT[cur][0];
            floatx4 acc0 = {0.f, 0.f, 0.f, 0.f};
            floatx4 acc1 = {0.f, 0.f, 0.f, 0.f};
            floatx4 accd = {0.f, 0.f, 0.f, 0.f};
            #pragma unroll
            for (int ks = 0; ks < NKS_; ++ks) {
                ushort qiu = *(const ushort*)(qb + qiu_off[ks]);
                unsigned qi2 = ((unsigned)qiu << 16) | qiu;
                U8 qv; qv.u[0] = qi2; qv.u[1] = qi2; qv.u[2] = qi2; qv.u[3] = qi2;
                half8v qrow = *(const half8v*)(qb + qrow_off[ks]);
                half8v afr = qv.h * qrow;            // pq fragment, built once
                half8v b00 = *(const half8v*)(sb + b0o0 + ks * 64);
                half8v b01 = *(const half8v*)(sb + b0o1 + ks * 64);
                acc0 = __builtin_amdgcn_mfma_f32_16x16x32_f16(afr, b00, acc0, 0, 0, 0);
                acc1 = __builtin_amdgcn_mfma_f32_16x16x32_f16(afr, b01, acc1, 0, 0, 0);
                if (den_w) {
                    half8v b1 = (half8v){0, 0, 0, 0, 0, 0, 0, 0};
                    if (nlane == 0) b1 = *(const half8v*)&sk_s[cur][ks * 32 + quad * 8];
                    accd = __builtin_amdgcn_mfma_f32_16x16x32_f16(afr, b1, accd, 0, 0, 0);
                }
            }
            _Float16* pp = ppart + ((size_t)(n * CHUNK_ + mt * 16 + quad * 4) << 6);
            #pragma unroll
            for (int r = 0; r < 4; ++r) {
                pp[(size_t)r << 6] = (_Float16)acc0[r];
                pp[((size_t)r << 6) + 16] = (_Float16)acc1[r];
            }
            if (den_w && nlane == 0) {
                #pragma unroll
                for (int r = 0; r < 4; ++r)
                    atomicAdd(&den_buf[(size_t)bh * T_ + n * CHUNK_ + mt * 16 + quad * 4 + r], accd[r]);
            }
        }

        // ======== MM2: S-hat(n+1) = gse*S-hat(n) + v^T.pk -> sT[nxt] (skip n=63)
        if (n < NCH_ - 1) {
            const char* kb = (const char*)&kTs[cur][0];
            const char* vb = (const char*)&vTs[cur][0];
            #pragma unroll
            for (int ts = 0; ts < 3; ++ts) {
                if (ts >= NTS) continue;
                #pragma unroll
                for (int m = 0; m < 4; ++m)
                    #pragma unroll
                    for (int r = 0; r < 4; ++r) res[ts][m][r] *= gsev;
                resk[ts][0] *= gsev;
            }
            #pragma unroll
            for (int k2 = 0; k2 < 2; ++k2) {
                const int xo = k2 * 64;    // c-group bit2 flip == byte bit6 flip
                half8v af0 = *(const half8v*)(vb + (af_off[0] ^ xo));
                half8v af1 = *(const half8v*)(vb + (af_off[1] ^ xo));
                half8v af2 = *(const half8v*)(vb + (af_off[2] ^ xo));
                half8v af3 = *(const half8v*)(vb + (af_off[3] ^ xo));
                #pragma unroll
                for (int ts = 0; ts < 3; ++ts) {
                    if (ts >= NTS) continue;
                    half8v pa = *(const half8v*)(kb + (pa_off[ts] ^ xo));
                    half8v pb = *(const half8v*)(kb + (pb_off[ts] ^ xo));
                    U8 mv; mv.u[0] = m2sp[ts]; mv.u[1] = m2sp[ts]; mv.u[2] = m2sp[ts]; mv.u[3] = m2sp[ts];
                    half8v bfr = pa * pb * mv.h;     // built ONCE for all 4 m + sk
                    res[ts][0] = __builtin_amdgcn_mfma_f32_16x16x32_f16(af0, bfr, res[ts][0], 0, 0, 0);
                    res[ts][1] = __builtin_amdgcn_mfma_f32_16x16x32_f16(af1, bfr, res[ts][1], 0, 0, 0);
                    res[ts][2] = __builtin_amdgcn_mfma_f32_16x16x32_f16(af2, bfr, res[ts][2], 0, 0, 0);
                    res[ts][3] = __builtin_amdgcn_mfma_f32_16x16x32_f16(af3, bfr, res[ts][3], 0, 0, 0);
                    resk[ts] = __builtin_amdgcn_mfma_f32_16x16x32_f16(af_sk, bfr, resk[ts], 0, 0, 0);
                }
            }
            // write back S-hat(n+1) into sT[nxt] (swizzled, 2-way max) + sk[nxt]
            char* stb = (char*)&sT[nxt][0];
            #pragma unroll
            for (int ts = 0; ts < 3; ++ts) {
                if (ts >= NTS) continue;
                #pragma unroll
                for (int m = 0; m < 4; ++m)
                    #pragma unroll
                    for (int r = 0; r < 4; ++r)
                        *(_Float16*)(stb + stw_off[ts] + (m * 16 * STR_ + r * STR_) * 2) =
                            (_Float16)res[ts][m][r];
                if (quad == 0) sk_s[nxt][eidx[ts]] = (_Float16)resk[ts][0];
            }
        }

        __syncthreads();   // single barrier: staging drained; sT/sk[nxt] visible
    }
}

// ---------------- Kernel A+C: intra-chunk attention (f16 MFMA) + merge ----------------
__global__ __launch_bounds__(256) void intra_merge_kernel(
    const _Float16* __restrict__ qh, const _Float16* __restrict__ kh,
    const _Float16* __restrict__ vhT, const float* __restrict__ gse_buf,
    const float* __restrict__ den_buf, const _Float16* __restrict__ part,
    float* __restrict__ out)
{
    const int bid = blockIdx.x;
    const int n = bid & 63, h = (bid >> 6) & 15, b = bid >> 10;
    const int tid = threadIdx.x;
    const int lane = tid & 63, w = tid >> 6;     // 4 waves
    const int nlane = lane & 15, quad = lane >> 4;
    const int t0 = n * CHUNK_;
    const int bh = b * H_ + h;

    __shared__ __align__(16) _Float16 qs[4096];   // q~ [c][d-swz]
    __shared__ __align__(16) _Float16 ksm[4096];  // k~ [m][d-swz]
    __shared__ __align__(16) _Float16 vs[4096];   // v^T [d][c-swz]
    __shared__ __align__(16) _Float16 ss[4096];   // s  [c][m-swz] f16
    __shared__ float nbuf[64 * 68];
    __shared__ float dens[64];

    const size_t obase = (size_t)(bh * NCH_ + n) * 4096;
    gload16(qh + obase + tid * 8, &qs[tid * 8]);
    gload16(qh + obase + 2048 + tid * 8, &qs[2048 + tid * 8]);
    gload16(kh + obase + tid * 8, &ksm[tid * 8]);
    gload16(kh + obase + 2048 + tid * 8, &ksm[2048 + tid * 8]);
    gload16(vhT + obase + tid * 8, &vs[tid * 8]);
    gload16(vhT + obase + 2048 + tid * 8, &vs[2048 + tid * 8]);
    const float gsei = 1.0f / gse_buf[bh * NCH_ + n];
    __syncthreads();

    const int ct = w;
    const int crow = ct * 16 + nlane;
    const int cswz = crow & 7;

    // ======== QK^T: qk~[c][m] = sum_d q~[c][d] k~[m][d]  (16x16x32, K=d)
    floatx4 qk[4];
    #pragma unroll
    for (int mt = 0; mt < 4; ++mt) qk[mt] = (floatx4){0.f, 0.f, 0.f, 0.f};
    #pragma unroll
    for (int ks_ = 0; ks_ < 2; ++ks_) {
        int g = ks_ * 4 + quad;
        half8v a = *(const half8v*)&qs[crow * 64 + ((g ^ cswz) << 3)];
        #pragma unroll
        for (int mt = 0; mt < 4; ++mt) {
            int mrow = mt * 16 + nlane;
            half8v bf = *(const half8v*)&ksm[mrow * 64 + ((g ^ (mrow & 7)) << 3)];
            qk[mt] = __builtin_amdgcn_mfma_f32_16x16x32_f16(a, bf, qk[mt], 0, 0, 0);
        }
    }

    // ======== scores: s = qk~^2 * e^{-gs} * [m<=c]; den row-sum in-register
    float dsum[4] = {0.f, 0.f, 0.f, 0.f};
    #pragma unroll
    for (int mt = 0; mt < 4; ++mt) {
        int m = mt * 16 + nlane;
        #pragma unroll
        for (int r = 0; r < 4; ++r) {
            int c = ct * 16 + quad * 4 + r;
            float sv = qk[mt][r];
            sv = sv * sv * gsei;
            sv = (m <= c) ? sv : 0.f;
            dsum[r] += sv;
            ss[c * 64 + (((m >> 3) ^ (c & 7)) << 3) + (m & 7)] = (_Float16)sv;
        }
    }
    #pragma unroll
    for (int off = 1; off < 16; off <<= 1)
        #pragma unroll
        for (int r = 0; r < 4; ++r) dsum[r] += __shfl_xor(dsum[r], off, 64);
    if (nlane == 0) {
        #pragma unroll
        for (int r = 0; r < 4; ++r) dens[ct * 16 + quad * 4 + r] = dsum[r];
    }
    __syncthreads();   // ss + dens visible (defensive; ss deps are intra-wave)

    // ======== PV: num[c][d] = sum_m s[c][m] v[m][d]  (16x16x32, K=m)
    floatx4 num[4];
    #pragma unroll
    for (int dt = 0; dt < 4; ++dt) num[dt] = (floatx4){0.f, 0.f, 0.f, 0.f};
    #pragma unroll
    for (int ks_ = 0; ks_ < 2; ++ks_) {
        int g = ks_ * 4 + quad;
        half8v a = *(const half8v*)&ss[crow * 64 + ((g ^ cswz) << 3)];
        #pragma unroll
        for (int dt = 0; dt < 4; ++dt) {
            int d = dt * 16 + nlane, dl = d & 31;
            int f = (dl & 7) ^ (dl >> 3);
            half8v bf = *(const half8v*)&vs[d * 64 + ((g ^ f) << 3)];
            num[dt] = __builtin_amdgcn_mfma_f32_16x16x32_f16(a, bf, num[dt], 0, 0, 0);
        }
    }
    #pragma unroll
    for (int dt = 0; dt < 4; ++dt)
        #pragma unroll
        for (int r = 0; r < 4; ++r)
            nbuf[(ct * 16 + quad * 4 + r) * 68 + dt * 16 + nlane] = num[dt][r];
    __syncthreads();

    // ======== tail: add inter parts, divide, store
    for (int idx = tid; idx < 4096; idx += 256) {
        int c = idx >> 6, d = idx & 63;
        float sum = nbuf[c * 68 + d];
        size_t pb = (((size_t)bh * T_ + t0 + c) << 6) + d;
        #pragma unroll
        for (int ehh = 0; ehh < EH_; ++ehh)
            sum += (float)part[(size_t)ehh * OUTN_ + pb];
        float den = dens[c] + den_buf[(size_t)bh * T_ + t0 + c];
        out[((size_t)(b * T_ + t0 + c) * H_ + h) * 64 + d] = sum / fmaxf(den, 1.0f);
    }
}

extern "C" void kernel_launch(void* const* d_in, const int* in_sizes, int n_in,
                              void* d_out, int out_size, void* d_ws, size_t ws_size,
                              hipStream_t stream)
{
    (void)in_sizes; (void)n_in; (void)out_size; (void)ws_size;
    const float* q   = (const float*)d_in[0];
    const float* k   = (const float*)d_in[1];
    const float* v   = (const float*)d_in[2];
    const float* g   = (const float*)d_in[3];
    const float* S0  = (const float*)d_in[4];
    const float* sk0 = (const float*)d_in[5];
    float* out = (float*)d_out;

    // ws: den f32 | part f16 [EH][BHT D] | qh/khT/vhT/kh f16 (16.78MB each) | gse f32
    char* wp = (char*)d_ws;
    float*    den_buf = (float*)wp;                 wp += (size_t)B_ * H_ * T_ * sizeof(float);
    _Float16* part    = (_Float16*)wp;              wp += (size_t)EH_ * OUTN_ * sizeof(_Float16);
    _Float16* qh      = (_Float16*)wp;              wp += (size_t)B_ * H_ * T_ * D_ * sizeof(_Float16);
    _Float16* khT     = (_Float16*)wp;              wp += (size_t)B_ * H_ * T_ * D_ * sizeof(_Float16);
    _Float16* vhT     = (_Float16*)wp;              wp += (size_t)B_ * H_ * T_ * D_ * sizeof(_Float16);
    _Float16* kh      = (_Float16*)wp;              wp += (size_t)B_ * H_ * T_ * D_ * sizeof(_Float16);
    float*    gse_buf = (float*)wp;

    hipMemsetAsync(den_buf, 0, (size_t)B_ * H_ * T_ * sizeof(float), stream);
    prep_kernel<<<dim3(2048), dim3(256), 0, stream>>>(q, k, v, g, qh, kh, khT, vhT, gse_buf);
    scan_kernel<<<dim3(256), dim3(512), 0, stream>>>(qh, khT, vhT, gse_buf, S0, sk0, den_buf, part);
    intra_merge_kernel<<<dim3(2048), dim3(256), 0, stream>>>(qh, kh, vhT, gse_buf, den_buf, part, out);
}

// Round 9
// 399.600 us; speedup vs baseline: 1.3647x; 1.0055x over previous
//
#include <hip/hip_runtime.h>

// Power retention (deg-2), B=2 T=4096 H=16 D=64, CHUNK=64, E=2080.
// Round 12: R11 (401.8us) + vectorized merge tail. The old tail did 128
// scalar 2B part loads per thread (8 eh x 16 iters) — Common-mistake #2 in
// our own kernel. New tail: half8v part loads (16B/lane, 1KB/wave-instr),
// float4 out stores, one reciprocal per 8 outputs. scan + prep verbatim.

#define B_ 2
#define T_ 4096
#define H_ 16
#define D_ 64
#define CHUNK_ 64
#define NCH_ 64
#define E_ 2080
#define EH_ 8
#define NBLK_ 36         // (i, jb) 8-wide blocks per eh-slice (288/8, exact)
#define EPAD_ 288        // NBLK_*8
#define NKS_ 9           // MM1 K-steps of 32
#define STR_ 296         // sT row stride (f16), 592B
#define OUTN_ 8388608    // B*T*H*D

typedef __attribute__((ext_vector_type(8))) _Float16 half8v;
typedef __attribute__((ext_vector_type(4))) float floatx4;

union U8 { half8v h; unsigned u[4]; ushort s[8]; };

static __device__ __forceinline__ float wave_iscan(float g, int lane) {
    #pragma unroll
    for (int off = 1; off < 64; off <<= 1) {
        float o = __shfl_up(g, off, 64);
        if (lane >= off) g += o;
    }
    return g;
}

typedef const __attribute__((address_space(1))) unsigned int* gas1_t;
typedef __attribute__((address_space(3))) unsigned int* las3_t;
static __device__ __forceinline__ void gload16(const void* g, void* l) {
    __builtin_amdgcn_global_load_lds((gas1_t)g, (las3_t)l, 16, 0, 0);
}

// ---------------- Prep: gates + scales + cvt + swizzled transpose ----------------
// qh : [bh][n][c][ ((d>>3) ^ (c&7))*8 + (d&7) ]            q~ = 0.125*exp(0.5*cg)*q
// kh : [bh][n][c][ ((d>>3) ^ (c&7))*8 + (d&7) ]            k~ = exp(0.5*(gs-cg))*k
// khT: [bh][n][d][ ((c>>3) ^ (d&7) ^ (d>>3))*8 + (c&7) ]
// vhT: [bh][n][d][ ((c>>3) ^ (dl&7) ^ (dl>>3))*8 + (c&7) ] dl = d&31
__global__ __launch_bounds__(256) void prep_kernel(
    const float* __restrict__ q, const float* __restrict__ k, const float* __restrict__ v,
    const float* __restrict__ gate,
    _Float16* __restrict__ qh, _Float16* __restrict__ kh, _Float16* __restrict__ khT,
    _Float16* __restrict__ vhT, float* __restrict__ gse_buf)
{
    const int bid = blockIdx.x;          // bh*64 + n
    const int bh = bid >> 6, n = bid & 63;
    const int b = bh >> 4, h = bh & 15;
    const int t0 = n * CHUNK_;
    const int tid = threadIdx.x;

    __shared__ float cgs[64];
    __shared__ float tbuf[64 * 68];

    if (tid < 64) {
        float g = gate[((size_t)(b * T_ + t0) + tid) * H_ + h];
        cgs[tid] = wave_iscan(g, tid);
    }
    __syncthreads();
    const float gs = cgs[63];
    if (tid == 0) gse_buf[bid] = __expf(gs);

    const int c = tid >> 2, dq = (tid & 3) * 16;
    const size_t gbase = ((size_t)(b * T_ + t0 + c) * H_ + h) * 64 + dq;
    const size_t obase = (size_t)bid * 4096;

    // ---- q~ (no transpose, swizzled d-groups)
    {
        float qsc = 0.125f * __expf(0.5f * cgs[c]);
        #pragma unroll
        for (int g8 = 0; g8 < 2; ++g8) {
            float4 a0 = *(const float4*)(q + gbase + g8 * 8);
            float4 a1 = *(const float4*)(q + gbase + g8 * 8 + 4);
            half8v hv;
            hv[0] = (_Float16)(a0.x * qsc); hv[1] = (_Float16)(a0.y * qsc);
            hv[2] = (_Float16)(a0.z * qsc); hv[3] = (_Float16)(a0.w * qsc);
            hv[4] = (_Float16)(a1.x * qsc); hv[5] = (_Float16)(a1.y * qsc);
            hv[6] = (_Float16)(a1.z * qsc); hv[7] = (_Float16)(a1.w * qsc);
            int grp = (dq >> 3) + g8;
            *(half8v*)&qh[obase + (size_t)(c * 64) + ((grp ^ (c & 7)) << 3)] = hv;
        }
    }
    // ---- k~ -> kh (row-major, q-style swizzle) + LDS [c][d]
    {
        float ksc = __expf(0.5f * (gs - cgs[c]));
        float4 sa[4];
        #pragma unroll
        for (int i = 0; i < 4; ++i) {
            float4 a = *(const float4*)(k + gbase + i * 4);
            sa[i].x = a.x * ksc; sa[i].y = a.y * ksc;
            sa[i].z = a.z * ksc; sa[i].w = a.w * ksc;
            *(float4*)&tbuf[c * 68 + dq + i * 4] = sa[i];
        }
        #pragma unroll
        for (int g8 = 0; g8 < 2; ++g8) {
            half8v hv;
            hv[0] = (_Float16)sa[g8 * 2].x;     hv[1] = (_Float16)sa[g8 * 2].y;
            hv[2] = (_Float16)sa[g8 * 2].z;     hv[3] = (_Float16)sa[g8 * 2].w;
            hv[4] = (_Float16)sa[g8 * 2 + 1].x; hv[5] = (_Float16)sa[g8 * 2 + 1].y;
            hv[6] = (_Float16)sa[g8 * 2 + 1].z; hv[7] = (_Float16)sa[g8 * 2 + 1].w;
            int grp = (dq >> 3) + g8;
            *(half8v*)&kh[obase + (size_t)(c * 64) + ((grp ^ (c & 7)) << 3)] = hv;
        }
    }
    __syncthreads();
    {   // transposed, swizzled store of k~^T
        int d = tid & 63, f = (d & 7) ^ (d >> 3);
        #pragma unroll
        for (int gg = 0; gg < 2; ++gg) {
            int cg = (tid >> 6) * 2 + gg;
            half8v hv;
            #pragma unroll
            for (int j = 0; j < 8; ++j) hv[j] = (_Float16)tbuf[(cg * 8 + j) * 68 + d];
            *(half8v*)&khT[obase + (size_t)(d * 64) + ((cg ^ f) << 3)] = hv;
        }
    }
    __syncthreads();
    {   // v -> LDS (no scale)
        #pragma unroll
        for (int i = 0; i < 4; ++i)
            *(float4*)&tbuf[c * 68 + dq + i * 4] = *(const float4*)(v + gbase + i * 4);
    }
    __syncthreads();
    {   // transposed, swizzled store of v^T (f over dl = d&31)
        int d = tid & 63, dl = d & 31, f = (dl & 7) ^ (dl >> 3);
        #pragma unroll
        for (int gg = 0; gg < 2; ++gg) {
            int cg = (tid >> 6) * 2 + gg;
            half8v hv;
            #pragma unroll
            for (int j = 0; j < 8; ++j) hv[j] = (_Float16)tbuf[(cg * 8 + j) * 68 + d];
            *(half8v*)&vhT[obase + (size_t)(d * 64) + ((cg ^ f) << 3)] = hv;
        }
    }
}

// ---------------- Kernel B: dh-merged single-barrier double-buffered scan ----------------
__global__ __launch_bounds__(512, 2) void scan_kernel(
    const _Float16* __restrict__ qh, const _Float16* __restrict__ khT,
    const _Float16* __restrict__ vhT, const float* __restrict__ gse_buf,
    const float* __restrict__ S0, const float* __restrict__ sk0,
    float* __restrict__ den_buf, _Float16* __restrict__ part)
{
    const int bid = blockIdx.x;          // 256 blocks
    // XCD swizzle: all 8 eh-blocks of one bh share bid&7 -> same XCD
    const int bh = (bid & 7) * 4 + (bid >> 6);
    const int eh = (bid >> 3) & 7;
    const int tid = threadIdx.x, lane = tid & 63, w = tid >> 6;   // w 0..7
    const int nlane = lane & 15, quad = lane >> 4;

    __shared__ __align__(16) _Float16 sT[2][64 * STR_]; // S^T[d][e], 2-bit XOR swz, 75.8KB
    __shared__ __align__(16) _Float16 kTs[2][4096];     // k~^T (linear, global-preswizzled)
    __shared__ __align__(16) _Float16 qsh[2][4096];     // q~   (linear, global-preswizzled)
    __shared__ __align__(16) _Float16 vTs[2][4096];     // v^T full d (linear, preswizzled)
    __shared__ __align__(16) _Float16 sk_s[2][EPAD_];
    __shared__ int blk_s[NBLK_];                        // i | (jb<<8)

    // ---- build (i, jb) block table for this slice
    for (int t = tid; t < NBLK_; t += 512) {
        int g = eh * NBLK_ + t;
        int i = 0;
        while (g >= 8 - (i >> 3)) { g -= 8 - (i >> 3); ++i; }
        int jb = (i >> 3) + g;
        blk_s[t] = i | (jb << 8);
    }
    __syncthreads();

    const _Float16* qsrc = qh + (size_t)(bh * NCH_) * 4096;
    const _Float16* ksrc = khT + (size_t)(bh * NCH_) * 4096;
    const _Float16* vsrc = vhT + (size_t)(bh * NCH_) * 4096;

    // ---- prologue: stage chunk 0 into buffer 0; drains at B0
    gload16(qsrc + tid * 8, &qsh[0][tid * 8]);
    gload16(ksrc + tid * 8, &kTs[0][tid * 8]);
    gload16(vsrc + tid * 8, &vTs[0][tid * 8]);

    // ---- sk[0] init (sqrt2 fold; invalid slots stay 0 forever)
    for (int e = tid; e < EPAD_; e += 512) {
        int bv = blk_s[e >> 3];
        int i = bv & 255, j8 = (bv >> 8) * 8 + (e & 7);
        float sv = 0.f;
        if (j8 >= i) {
            int er = (i * (129 - i)) / 2 + (j8 - i);
            float coef = (j8 == i) ? 1.f : 1.41421356237f;
            sv = sk0[(size_t)bh * E_ + er] * coef;
        }
        sk_s[0][e] = (_Float16)sv;
    }
    // ---- sT[0] init (f16 copy of S-hat = coef * S0), 2-bit XOR swizzled columns
    for (int p = tid; p < 64 * EPAD_; p += 512) {
        int d = p / EPAD_;
        int e = p - d * EPAD_;
        int bv = blk_s[e >> 3];
        int i = bv & 255, j8 = (bv >> 8) * 8 + (e & 7);
        float sv = 0.f;
        if (j8 >= i) {
            int er = (i * (129 - i)) / 2 + (j8 - i);
            float coef = (j8 == i) ? 1.f : 1.41421356237f;
            sv = S0[((size_t)bh * E_ + er) * 64 + d] * coef;
        }
        int col8 = e >> 3, gsw = (d >> 2) & 3;
        int pc = ((col8 & ~3) | ((col8 & 3) ^ gsw)) * 8 + (e & 7);
        sT[0][d * STR_ + pc] = (_Float16)sv;
    }

    // ---- wave roles: MM1 wave (mt = w&3, nth = w>>2 covering d-cols nth*32..+31);
    //      MM2 wave owns tiles {w, w+8, (w+16 if w<2)} x m 0..3 (+sk)
    const int mt = w & 3, nth = w >> 2;
    const int c_row = mt * 16 + nlane;
    const bool den_w = (w < 4);
    const int NTS = (w < 2) ? 3 : 2;

    // ---- resident S fragments
    floatx4 res[3][4];
    floatx4 resk[3];
    #pragma unroll
    for (int ts = 0; ts < 3; ++ts) {
        #pragma unroll
        for (int m = 0; m < 4; ++m) res[ts][m] = (floatx4){0.f, 0.f, 0.f, 0.f};
        resk[ts] = (floatx4){0.f, 0.f, 0.f, 0.f};
        if (ts >= NTS) continue;
        int tile = w + 8 * ts;
        int e = tile * 16 + nlane;
        int bv = blk_s[e >> 3];
        int i = bv & 255, j8 = (bv >> 8) * 8 + (e & 7);
        if (j8 >= i) {
            int er = (i * (129 - i)) / 2 + (j8 - i);
            float coef = (j8 == i) ? 1.f : 1.41421356237f;
            #pragma unroll
            for (int m = 0; m < 4; ++m) {
                floatx4 t4 = *(const floatx4*)&S0[((size_t)bh * E_ + er) * 64 + m * 16 + quad * 4];
                #pragma unroll
                for (int r = 0; r < 4; ++r) res[ts][m][r] = t4[r] * coef;
            }
            if (quad == 0) resk[ts][0] = sk0[(size_t)bh * E_ + er] * coef;
        }
    }

    // ---- chunk-invariant MM1 addresses (byte offsets, within-buffer)
    int qiu_off[NKS_], qrow_off[NKS_];
    #pragma unroll
    for (int ks = 0; ks < NKS_; ++ks) {
        int bv = blk_s[ks * 4 + quad];
        int ib = bv & 255, jb = bv >> 8;
        qiu_off[ks]  = (c_row * 64 + (((ib >> 3) ^ (c_row & 7)) << 3) + (ib & 7)) * 2;
        qrow_off[ks] = (c_row * 64 + ((jb ^ (c_row & 7)) << 3)) * 2;
    }
    const int swzb = (quad ^ ((nlane >> 2) & 3)) << 3;
    const int b0o0 = ((nth * 32 + nlane) * STR_ + swzb) * 2;
    const int b0o1 = ((nth * 32 + 16 + nlane) * STR_ + swzb) * 2;

    // ---- chunk-invariant MM2 addresses + m2 splats
    int pa_off[3], pb_off[3], stw_off[3], eidx[3];
    unsigned m2sp[3];
    #pragma unroll
    for (int ts = 0; ts < 3; ++ts) {
        pa_off[ts] = pb_off[ts] = stw_off[ts] = eidx[ts] = 0; m2sp[ts] = 0;
        if (ts >= NTS) continue;
        int tile = w + 8 * ts, e = tile * 16 + nlane;
        int bv = blk_s[e >> 3];
        int ib = bv & 255, j8 = (bv >> 8) * 8 + (e & 7);
        int fib = (ib & 7) ^ (ib >> 3), fj8 = (j8 & 7) ^ (j8 >> 3);
        pa_off[ts] = (ib * 64 + ((quad ^ fib) << 3)) * 2;
        pb_off[ts] = (j8 * 64 + ((quad ^ fj8) << 3)) * 2;
        int col8 = e >> 3;
        int pc = ((col8 & ~3) | ((col8 & 3) ^ quad)) * 8 + (e & 7);
        stw_off[ts] = (quad * 4 * STR_ + pc) * 2;
        eidx[ts] = e;
        unsigned hv = (j8 < ib) ? 0u : ((j8 == ib) ? 0x3C00u : 0x4000u);  // {0,1,2} coef^2
        m2sp[ts] = (hv << 16) | hv;
    }
    int af_off[4];
    #pragma unroll
    for (int m = 0; m < 4; ++m) {
        int row = m * 16 + nlane, dl = row & 31;
        int fr = (dl & 7) ^ (dl >> 3);
        af_off[m] = (row * 64 + ((quad ^ fr) << 3)) * 2;
    }
    half8v af_sk = (half8v){0, 0, 0, 0, 0, 0, 0, 0};
    if (nlane == 0) af_sk = (half8v){1, 1, 1, 1, 1, 1, 1, 1};

    _Float16* ppart = part + (size_t)eh * OUTN_ + (((size_t)bh * T_) << 6) + nth * 32 + nlane;

    __syncthreads();   // B0: init done; chunk-0 staging drained

    for (int n = 0; n < NCH_; ++n) {
        const int cur = n & 1, nxt = cur ^ 1;

        // ---- stage chunk n+1 into [nxt]; drains at this chunk's barrier
        if (n + 1 < NCH_) {
            gload16(qsrc + (size_t)(n + 1) * 4096 + tid * 8, &qsh[nxt][tid * 8]);
            gload16(ksrc + (size_t)(n + 1) * 4096 + tid * 8, &kTs[nxt][tid * 8]);
            gload16(vsrc + (size_t)(n + 1) * 4096 + tid * 8, &vTs[nxt][tid * 8]);
        }
        const float gsev = gse_buf[bh * NCH_ + n];

        // ======== MM1: num[c][d] = pq . S-hat(n), d-cols nth*32..+31; den rides
        {
            const char* qb = (const char*)&qsh[cur][0];
            const char* sb = (const char*)&sT[cur][0];
            floatx4 acc0 = {0.f, 0.f, 0.f, 0.f};
            floatx4 acc1 = {0.f, 0.f, 0.f, 0.f};
            floatx4 accd = {0.f, 0.f, 0.f, 0.f};
            #pragma unroll
            for (int ks = 0; ks < NKS_; ++ks) {
                ushort qiu = *(const ushort*)(qb + qiu_off[ks]);
                unsigned qi2 = ((unsigned)qiu << 16) | qiu;
                U8 qv; qv.u[0] = qi2; qv.u[1] = qi2; qv.u[2] = qi2; qv.u[3] = qi2;
                half8v qrow = *(const half8v*)(qb + qrow_off[ks]);
                half8v afr = qv.h * qrow;            // pq fragment, built once
                half8v b00 = *(const half8v*)(sb + b0o0 + ks * 64);
                half8v b01 = *(const half8v*)(sb + b0o1 + ks * 64);
                acc0 = __builtin_amdgcn_mfma_f32_16x16x32_f16(afr, b00, acc0, 0, 0, 0);
                acc1 = __builtin_amdgcn_mfma_f32_16x16x32_f16(afr, b01, acc1, 0, 0, 0);
                if (den_w) {
                    half8v b1 = (half8v){0, 0, 0, 0, 0, 0, 0, 0};
                    if (nlane == 0) b1 = *(const half8v*)&sk_s[cur][ks * 32 + quad * 8];
                    accd = __builtin_amdgcn_mfma_f32_16x16x32_f16(afr, b1, accd, 0, 0, 0);
                }
            }
            _Float16* pp = ppart + ((size_t)(n * CHUNK_ + mt * 16 + quad * 4) << 6);
            #pragma unroll
            for (int r = 0; r < 4; ++r) {
                pp[(size_t)r << 6] = (_Float16)acc0[r];
                pp[((size_t)r << 6) + 16] = (_Float16)acc1[r];
            }
            if (den_w && nlane == 0) {
                #pragma unroll
                for (int r = 0; r < 4; ++r)
                    atomicAdd(&den_buf[(size_t)bh * T_ + n * CHUNK_ + mt * 16 + quad * 4 + r], accd[r]);
            }
        }

        // ======== MM2: S-hat(n+1) = gse*S-hat(n) + v^T.pk -> sT[nxt] (skip n=63)
        if (n < NCH_ - 1) {
            const char* kb = (const char*)&kTs[cur][0];
            const char* vb = (const char*)&vTs[cur][0];
            #pragma unroll
            for (int ts = 0; ts < 3; ++ts) {
                if (ts >= NTS) continue;
                #pragma unroll
                for (int m = 0; m < 4; ++m)
                    #pragma unroll
                    for (int r = 0; r < 4; ++r) res[ts][m][r] *= gsev;
                resk[ts][0] *= gsev;
            }
            #pragma unroll
            for (int k2 = 0; k2 < 2; ++k2) {
                const int xo = k2 * 64;    // c-group bit2 flip == byte bit6 flip
                half8v af0 = *(const half8v*)(vb + (af_off[0] ^ xo));
                half8v af1 = *(const half8v*)(vb + (af_off[1] ^ xo));
                half8v af2 = *(const half8v*)(vb + (af_off[2] ^ xo));
                half8v af3 = *(const half8v*)(vb + (af_off[3] ^ xo));
                #pragma unroll
                for (int ts = 0; ts < 3; ++ts) {
                    if (ts >= NTS) continue;
                    half8v pa = *(const half8v*)(kb + (pa_off[ts] ^ xo));
                    half8v pb = *(const half8v*)(kb + (pb_off[ts] ^ xo));
                    U8 mv; mv.u[0] = m2sp[ts]; mv.u[1] = m2sp[ts]; mv.u[2] = m2sp[ts]; mv.u[3] = m2sp[ts];
                    half8v bfr = pa * pb * mv.h;     // built ONCE for all 4 m + sk
                    res[ts][0] = __builtin_amdgcn_mfma_f32_16x16x32_f16(af0, bfr, res[ts][0], 0, 0, 0);
                    res[ts][1] = __builtin_amdgcn_mfma_f32_16x16x32_f16(af1, bfr, res[ts][1], 0, 0, 0);
                    res[ts][2] = __builtin_amdgcn_mfma_f32_16x16x32_f16(af2, bfr, res[ts][2], 0, 0, 0);
                    res[ts][3] = __builtin_amdgcn_mfma_f32_16x16x32_f16(af3, bfr, res[ts][3], 0, 0, 0);
                    resk[ts] = __builtin_amdgcn_mfma_f32_16x16x32_f16(af_sk, bfr, resk[ts], 0, 0, 0);
                }
            }
            // write back S-hat(n+1) into sT[nxt] (swizzled, 2-way max) + sk[nxt]
            char* stb = (char*)&sT[nxt][0];
            #pragma unroll
            for (int ts = 0; ts < 3; ++ts) {
                if (ts >= NTS) continue;
                #pragma unroll
                for (int m = 0; m < 4; ++m)
                    #pragma unroll
                    for (int r = 0; r < 4; ++r)
                        *(_Float16*)(stb + stw_off[ts] + (m * 16 * STR_ + r * STR_) * 2) =
                            (_Float16)res[ts][m][r];
                if (quad == 0) sk_s[nxt][eidx[ts]] = (_Float16)resk[ts][0];
            }
        }

        __syncthreads();   // single barrier: staging drained; sT/sk[nxt] visible
    }
}

// ---------------- Kernel A+C: intra-chunk attention (f16 MFMA) + merge ----------------
__global__ __launch_bounds__(256) void intra_merge_kernel(
    const _Float16* __restrict__ qh, const _Float16* __restrict__ kh,
    const _Float16* __restrict__ vhT, const float* __restrict__ gse_buf,
    const float* __restrict__ den_buf, const _Float16* __restrict__ part,
    float* __restrict__ out)
{
    const int bid = blockIdx.x;
    const int n = bid & 63, h = (bid >> 6) & 15, b = bid >> 10;
    const int tid = threadIdx.x;
    const int lane = tid & 63, w = tid >> 6;     // 4 waves
    const int nlane = lane & 15, quad = lane >> 4;
    const int t0 = n * CHUNK_;
    const int bh = b * H_ + h;

    __shared__ __align__(16) _Float16 qs[4096];   // q~ [c][d-swz]
    __shared__ __align__(16) _Float16 ksm[4096];  // k~ [m][d-swz]
    __shared__ __align__(16) _Float16 vs[4096];   // v^T [d][c-swz]
    __shared__ __align__(16) _Float16 ss[4096];   // s  [c][m-swz] f16
    __shared__ float nbuf[64 * 68];
    __shared__ float dens[64];

    const size_t obase = (size_t)(bh * NCH_ + n) * 4096;
    gload16(qh + obase + tid * 8, &qs[tid * 8]);
    gload16(qh + obase + 2048 + tid * 8, &qs[2048 + tid * 8]);
    gload16(kh + obase + tid * 8, &ksm[tid * 8]);
    gload16(kh + obase + 2048 + tid * 8, &ksm[2048 + tid * 8]);
    gload16(vhT + obase + tid * 8, &vs[tid * 8]);
    gload16(vhT + obase + 2048 + tid * 8, &vs[2048 + tid * 8]);
    const float gsei = 1.0f / gse_buf[bh * NCH_ + n];
    __syncthreads();

    const int ct = w;
    const int crow = ct * 16 + nlane;
    const int cswz = crow & 7;

    // ======== QK^T: qk~[c][m] = sum_d q~[c][d] k~[m][d]  (16x16x32, K=d)
    floatx4 qk[4];
    #pragma unroll
    for (int mt = 0; mt < 4; ++mt) qk[mt] = (floatx4){0.f, 0.f, 0.f, 0.f};
    #pragma unroll
    for (int ks_ = 0; ks_ < 2; ++ks_) {
        int g = ks_ * 4 + quad;
        half8v a = *(const half8v*)&qs[crow * 64 + ((g ^ cswz) << 3)];
        #pragma unroll
        for (int mt = 0; mt < 4; ++mt) {
            int mrow = mt * 16 + nlane;
            half8v bf = *(const half8v*)&ksm[mrow * 64 + ((g ^ (mrow & 7)) << 3)];
            qk[mt] = __builtin_amdgcn_mfma_f32_16x16x32_f16(a, bf, qk[mt], 0, 0, 0);
        }
    }

    // ======== scores: s = qk~^2 * e^{-gs} * [m<=c]; den row-sum in-register
    float dsum[4] = {0.f, 0.f, 0.f, 0.f};
    #pragma unroll
    for (int mt = 0; mt < 4; ++mt) {
        int m = mt * 16 + nlane;
        #pragma unroll
        for (int r = 0; r < 4; ++r) {
            int c = ct * 16 + quad * 4 + r;
            float sv = qk[mt][r];
            sv = sv * sv * gsei;
            sv = (m <= c) ? sv : 0.f;
            dsum[r] += sv;
            ss[c * 64 + (((m >> 3) ^ (c & 7)) << 3) + (m & 7)] = (_Float16)sv;
        }
    }
    #pragma unroll
    for (int off = 1; off < 16; off <<= 1)
        #pragma unroll
        for (int r = 0; r < 4; ++r) dsum[r] += __shfl_xor(dsum[r], off, 64);
    if (nlane == 0) {
        #pragma unroll
        for (int r = 0; r < 4; ++r) dens[ct * 16 + quad * 4 + r] = dsum[r];
    }
    __syncthreads();   // ss + dens visible (defensive; ss deps are intra-wave)

    // ======== PV: num[c][d] = sum_m s[c][m] v[m][d]  (16x16x32, K=m)
    floatx4 num[4];
    #pragma unroll
    for (int dt = 0; dt < 4; ++dt) num[dt] = (floatx4){0.f, 0.f, 0.f, 0.f};
    #pragma unroll
    for (int ks_ = 0; ks_ < 2; ++ks_) {
        int g = ks_ * 4 + quad;
        half8v a = *(const half8v*)&ss[crow * 64 + ((g ^ cswz) << 3)];
        #pragma unroll
        for (int dt = 0; dt < 4; ++dt) {
            int d = dt * 16 + nlane, dl = d & 31;
            int f = (dl & 7) ^ (dl >> 3);
            half8v bf = *(const half8v*)&vs[d * 64 + ((g ^ f) << 3)];
            num[dt] = __builtin_amdgcn_mfma_f32_16x16x32_f16(a, bf, num[dt], 0, 0, 0);
        }
    }
    #pragma unroll
    for (int dt = 0; dt < 4; ++dt)
        #pragma unroll
        for (int r = 0; r < 4; ++r)
            nbuf[(ct * 16 + quad * 4 + r) * 68 + dt * 16 + nlane] = num[dt][r];
    __syncthreads();

    // ======== tail: add inter parts (vectorized half8v), divide, store
    for (int idx = tid; idx < 512; idx += 256) {    // 64 c x 8 d-groups of 8
        int c = idx >> 3, g = idx & 7;
        float acc8[8];
        #pragma unroll
        for (int j = 0; j < 8; ++j) acc8[j] = nbuf[c * 68 + g * 8 + j];
        size_t pb = (((size_t)bh * T_ + t0 + c) << 6) + g * 8;
        #pragma unroll
        for (int ehh = 0; ehh < EH_; ++ehh) {
            half8v pv = *(const half8v*)&part[(size_t)ehh * OUTN_ + pb];
            #pragma unroll
            for (int j = 0; j < 8; ++j) acc8[j] += (float)pv[j];
        }
        float den = dens[c] + den_buf[(size_t)bh * T_ + t0 + c];
        float rden = 1.0f / fmaxf(den, 1.0f);
        float4 o0, o1;
        o0.x = acc8[0] * rden; o0.y = acc8[1] * rden;
        o0.z = acc8[2] * rden; o0.w = acc8[3] * rden;
        o1.x = acc8[4] * rden; o1.y = acc8[5] * rden;
        o1.z = acc8[6] * rden; o1.w = acc8[7] * rden;
        float* op = &out[((size_t)(b * T_ + t0 + c) * H_ + h) * 64 + g * 8];
        *(float4*)op = o0;
        *((float4*)op + 1) = o1;
    }
}

extern "C" void kernel_launch(void* const* d_in, const int* in_sizes, int n_in,
                              void* d_out, int out_size, void* d_ws, size_t ws_size,
                              hipStream_t stream)
{
    (void)in_sizes; (void)n_in; (void)out_size; (void)ws_size;
    const float* q   = (const float*)d_in[0];
    const float* k   = (const float*)d_in[1];
    const float* v   = (const float*)d_in[2];
    const float* g   = (const float*)d_in[3];
    const float* S0  = (const float*)d_in[4];
    const float* sk0 = (const float*)d_in[5];
    float* out = (float*)d_out;

    // ws: den f32 | part f16 [EH][BHT D] | qh/khT/vhT/kh f16 (16.78MB each) | gse f32
    char* wp = (char*)d_ws;
    float*    den_buf = (float*)wp;                 wp += (size_t)B_ * H_ * T_ * sizeof(float);
    _Float16* part    = (_Float16*)wp;              wp += (size_t)EH_ * OUTN_ * sizeof(_Float16);
    _Float16* qh      = (_Float16*)wp;              wp += (size_t)B_ * H_ * T_ * D_ * sizeof(_Float16);
    _Float16* khT     = (_Float16*)wp;              wp += (size_t)B_ * H_ * T_ * D_ * sizeof(_Float16);
    _Float16* vhT     = (_Float16*)wp;              wp += (size_t)B_ * H_ * T_ * D_ * sizeof(_Float16);
    _Float16* kh      = (_Float16*)wp;              wp += (size_t)B_ * H_ * T_ * D_ * sizeof(_Float16);
    float*    gse_buf = (float*)wp;

    hipMemsetAsync(den_buf, 0, (size_t)B_ * H_ * T_ * sizeof(float), stream);
    prep_kernel<<<dim3(2048), dim3(256), 0, stream>>>(q, k, v, g, qh, kh, khT, vhT, gse_buf);
    scan_kernel<<<dim3(256), dim3(512), 0, stream>>>(qh, khT, vhT, gse_buf, S0, sk0, den_buf, part);
    intra_merge_kernel<<<dim3(2048), dim3(256), 0, stream>>>(qh, kh, vhT, gse_buf, den_buf, part, out);
}